// Round 2
// baseline (6381.835 us; speedup 1.0000x reference)
//
#include <hip/hip_runtime.h>
#include <hip/hip_bf16.h>
#include <math.h>

#define BB 2
#define LL 4096
#define DM 1024
#define DIP 4240
#define DI 2048
#define NH 16
#define HD 128
#define DS 64
#define CDIM 2176
#define MROWS (BB*LL)

__device__ __forceinline__ float silu_f(float x) { return x / (1.f + expf(-x)); }
__device__ __forceinline__ float softplus_f(float x) {
    return fmaxf(x, 0.f) + log1pf(expf(-fabsf(x)));
}
__device__ __forceinline__ float bf2f(unsigned short u) {
    return __uint_as_float(((unsigned int)u) << 16);
}
__device__ __forceinline__ unsigned short f2bf(float f) {
    unsigned int x = __float_as_uint(f);
    return (unsigned short)((x + 0x7fff + ((x >> 16) & 1)) >> 16);
}

// ---------------------------------------------------------------------------
// C_bf16[M][N] = A_f32[M][K] * B_f32[N][K]^T   (64x64 tile, 256 thr, 4x4/thr)
// ---------------------------------------------------------------------------
__global__ __launch_bounds__(256)
void gemm_f32_bf16(const float* __restrict__ A, const float* __restrict__ Bw,
                   unsigned short* __restrict__ C, int M, int N, int K)
{
    __shared__ float As[16][68];
    __shared__ float Bs[16][68];
    const int t  = threadIdx.x;
    const int tx = t & 15;
    const int ty = t >> 4;
    const int bm = blockIdx.y * 64;
    const int bn = blockIdx.x * 64;

    float acc[4][4] = {};
    const int r   = t >> 2;
    const int kk0 = (t & 3) * 4;

    for (int k0 = 0; k0 < K; k0 += 16) {
        {
            float4 av = *reinterpret_cast<const float4*>(&A[(size_t)(bm + r) * K + k0 + kk0]);
            As[kk0 + 0][r] = av.x; As[kk0 + 1][r] = av.y;
            As[kk0 + 2][r] = av.z; As[kk0 + 3][r] = av.w;
        }
        {
            int gn = bn + r;
            float4 bv = make_float4(0.f, 0.f, 0.f, 0.f);
            if (gn < N)
                bv = *reinterpret_cast<const float4*>(&Bw[(size_t)gn * K + k0 + kk0]);
            Bs[kk0 + 0][r] = bv.x; Bs[kk0 + 1][r] = bv.y;
            Bs[kk0 + 2][r] = bv.z; Bs[kk0 + 3][r] = bv.w;
        }
        __syncthreads();
        #pragma unroll
        for (int kk = 0; kk < 16; kk++) {
            float4 av = *reinterpret_cast<const float4*>(&As[kk][ty * 4]);
            float4 bv = *reinterpret_cast<const float4*>(&Bs[kk][tx * 4]);
            float a4[4] = {av.x, av.y, av.z, av.w};
            float b4[4] = {bv.x, bv.y, bv.z, bv.w};
            #pragma unroll
            for (int i = 0; i < 4; i++)
                #pragma unroll
                for (int j = 0; j < 4; j++)
                    acc[i][j] = fmaf(a4[i], b4[j], acc[i][j]);
        }
        __syncthreads();
    }

    #pragma unroll
    for (int i = 0; i < 4; i++) {
        int gm = bm + ty * 4 + i;
        #pragma unroll
        for (int j = 0; j < 4; j++) {
            int gn = bn + tx * 4 + j;
            if (gn < N) C[(size_t)gm * N + gn] = f2bf(acc[i][j]);
        }
    }
}

// ---------------------------------------------------------------------------
// out_f32[M][N] (acc)= A_bf16[M via lda, optional row-reverse] * B_f32[N][K]^T
// ---------------------------------------------------------------------------
__global__ __launch_bounds__(256)
void gemm_bf16A(const unsigned short* __restrict__ A, int lda,
                const float* __restrict__ Bw, float* __restrict__ C,
                int M, int N, int K, int rev, int accum)
{
    __shared__ float As[16][68];
    __shared__ float Bs[16][68];
    const int t  = threadIdx.x;
    const int tx = t & 15;
    const int ty = t >> 4;
    const int bm = blockIdx.y * 64;
    const int bn = blockIdx.x * 64;

    float acc[4][4] = {};
    const int r   = t >> 2;
    const int kk0 = (t & 3) * 4;

    int gm_load = bm + r;
    int src_row = gm_load;
    if (rev) {
        int rr = gm_load & (LL - 1);
        src_row = (gm_load & ~(LL - 1)) + (LL - 1 - rr);
    }

    for (int k0 = 0; k0 < K; k0 += 16) {
        {
            ushort4 uv = *reinterpret_cast<const ushort4*>(&A[(size_t)src_row * lda + k0 + kk0]);
            As[kk0 + 0][r] = bf2f(uv.x); As[kk0 + 1][r] = bf2f(uv.y);
            As[kk0 + 2][r] = bf2f(uv.z); As[kk0 + 3][r] = bf2f(uv.w);
        }
        {
            int gn = bn + r;
            float4 bv = make_float4(0.f, 0.f, 0.f, 0.f);
            if (gn < N)
                bv = *reinterpret_cast<const float4*>(&Bw[(size_t)gn * K + k0 + kk0]);
            Bs[kk0 + 0][r] = bv.x; Bs[kk0 + 1][r] = bv.y;
            Bs[kk0 + 2][r] = bv.z; Bs[kk0 + 3][r] = bv.w;
        }
        __syncthreads();
        #pragma unroll
        for (int kk = 0; kk < 16; kk++) {
            float4 av = *reinterpret_cast<const float4*>(&As[kk][ty * 4]);
            float4 bv = *reinterpret_cast<const float4*>(&Bs[kk][tx * 4]);
            float a4[4] = {av.x, av.y, av.z, av.w};
            float b4[4] = {bv.x, bv.y, bv.z, bv.w};
            #pragma unroll
            for (int i = 0; i < 4; i++)
                #pragma unroll
                for (int j = 0; j < 4; j++)
                    acc[i][j] = fmaf(a4[i], b4[j], acc[i][j]);
        }
        __syncthreads();
    }

    #pragma unroll
    for (int i = 0; i < 4; i++) {
        int gm = bm + ty * 4 + i;
        #pragma unroll
        for (int j = 0; j < 4; j++) {
            int gn = bn + tx * 4 + j;
            if (gn < N) {
                size_t idx = (size_t)gm * N + gn;
                if (accum) C[idx] += acc[i][j];
                else       C[idx]  = acc[i][j];
            }
        }
    }
}

// ---------------------------------------------------------------------------
// Depthwise causal conv (k=4) + SiLU, bf16 in/out; dir=1 reads reversed.
// Output in branch coordinates.
// ---------------------------------------------------------------------------
__global__ __launch_bounds__(256)
void conv_kernel(const unsigned short* __restrict__ zx, const float* __restrict__ cw,
                 const float* __restrict__ cb, unsigned short* __restrict__ xc, int dir)
{
    int idx = blockIdx.x * 256 + threadIdx.x;
    int c = idx % CDIM;
    int rb = idx / CDIM;
    int rr = rb & (LL - 1);
    int b  = rb >> 12;
    float acc = cb[c];
    #pragma unroll
    for (int k = 0; k < 4; k++) {
        int rsrc = rr - 3 + k;
        if (rsrc >= 0) {
            int l = dir ? (LL - 1 - rsrc) : rsrc;
            acc = fmaf(cw[c * 4 + k], bf2f(zx[(size_t)(b * LL + l) * DIP + DI + c]), acc);
        }
    }
    xc[(size_t)rb * CDIM + c] = f2bf(silu_f(acc));
}

// ---------------------------------------------------------------------------
// Sequential SSD scan, dt+softplus fused, D*x fused; writes y+D*x IN PLACE
// into the x-columns of xc (safe: head-h block is sole reader/writer of its
// columns and stages to LDS before overwriting).
// ---------------------------------------------------------------------------
__global__ __launch_bounds__(256)
void ssd_scan(unsigned short* __restrict__ xc, const unsigned short* __restrict__ zx,
              const float* __restrict__ dtb, const float* __restrict__ A_log,
              const float* __restrict__ Dv, int dir)
{
    int bh = blockIdx.x;
    int b = bh >> 4, h = bh & 15;
    float Ah = -expf(A_log[h]);
    float Dh = Dv[h];
    float dtbh = dtb[h];

    __shared__ float xs[32][HD];
    __shared__ float Bs[32][DS];
    __shared__ float Cs[32][DS];
    __shared__ float dts[32];

    const int tid = threadIdx.x;
    const int p  = tid >> 1;
    const int nb = (tid & 1) * 32;

    float hreg[32];
    #pragma unroll
    for (int j = 0; j < 32; j++) hreg[j] = 0.f;

    for (int c0 = 0; c0 < LL; c0 += 32) {
        for (int i = tid; i < 32 * HD; i += 256) {
            int tt = i >> 7, pp = i & 127;
            xs[tt][pp] = bf2f(xc[(size_t)(b * LL + c0 + tt) * CDIM + h * HD + pp]);
        }
        for (int i = tid; i < 32 * DS; i += 256) {
            int tt = i >> 6, nn = i & 63;
            Bs[tt][nn] = bf2f(xc[(size_t)(b * LL + c0 + tt) * CDIM + DI + nn]);
            Cs[tt][nn] = bf2f(xc[(size_t)(b * LL + c0 + tt) * CDIM + DI + DS + nn]);
        }
        if (tid < 32) {
            int rr = c0 + tid;
            int l = dir ? (LL - 1 - rr) : rr;
            dts[tid] = softplus_f(bf2f(zx[(size_t)(b * LL + l) * DIP + (DIP - NH) + h]) + dtbh);
        }
        __syncthreads();

        for (int tt = 0; tt < 32; tt++) {
            float dtt = dts[tt];
            float dA = expf(dtt * Ah);
            float xv = xs[tt][p];
            float xdtp = dtt * xv;
            float yp = 0.f;
            #pragma unroll
            for (int j = 0; j < 32; j++) {
                hreg[j] = fmaf(hreg[j], dA, xdtp * Bs[tt][nb + j]);
                yp = fmaf(hreg[j], Cs[tt][nb + j], yp);
            }
            yp += __shfl_xor(yp, 1);
            if ((tid & 1) == 0)
                xc[(size_t)(b * LL + c0 + tt) * CDIM + h * HD + p] = f2bf(fmaf(Dh, xv, yp));
        }
        __syncthreads();
    }
}

// ---------------------------------------------------------------------------
// Gated RMSNorm, in place over the x-columns of xc.
// ---------------------------------------------------------------------------
__global__ __launch_bounds__(256)
void branch_final(unsigned short* __restrict__ xc, const unsigned short* __restrict__ zx,
                  const float* __restrict__ nw, int dir)
{
    int row = blockIdx.x;
    int rr = row & (LL - 1);
    int b  = row >> 12;
    int l  = dir ? (LL - 1 - rr) : rr;

    unsigned short* yrow = xc + (size_t)row * CDIM;
    const unsigned short* zrow = zx + (size_t)(b * LL + l) * DIP;

    float v[8];
    float ss = 0.f;
    #pragma unroll
    for (int i = 0; i < 8; i++) {
        int c = threadIdx.x + i * 256;
        float val = bf2f(yrow[c]) * silu_f(bf2f(zrow[c]));
        v[i] = val;
        ss = fmaf(val, val, ss);
    }
    #pragma unroll
    for (int o = 32; o > 0; o >>= 1) ss += __shfl_down(ss, o);
    __shared__ float red[4];
    if ((threadIdx.x & 63) == 0) red[threadIdx.x >> 6] = ss;
    __syncthreads();
    ss = red[0] + red[1] + red[2] + red[3];
    float scale = rsqrtf(ss * (1.f / DI) + 1e-5f);

    #pragma unroll
    for (int i = 0; i < 8; i++) {
        int c = threadIdx.x + i * 256;
        yrow[c] = f2bf(v[i] * scale * nw[c]);
    }
}

// ---------------------------------------------------------------------------
extern "C" void kernel_launch(void* const* d_in, const int* in_sizes, int n_in,
                              void* d_out, int out_size, void* d_ws, size_t ws_size,
                              hipStream_t stream)
{
    const float* u       = (const float*)d_in[0];
    const float* w_in    = (const float*)d_in[1];
    const float* conv_w  = (const float*)d_in[2];
    const float* conv_b  = (const float*)d_in[3];
    const float* conv_wb = (const float*)d_in[4];
    const float* conv_bb = (const float*)d_in[5];
    const float* dt_bias  = (const float*)d_in[6];
    const float* dt_biasb = (const float*)d_in[7];
    const float* A_log   = (const float*)d_in[8];
    const float* A_b_log = (const float*)d_in[9];
    const float* Dp      = (const float*)d_in[10];
    const float* D_b     = (const float*)d_in[11];
    const float* norm_w  = (const float*)d_in[12];
    const float* w_out   = (const float*)d_in[13];
    float* out = (float*)d_out;

    unsigned short* zx = (unsigned short*)d_ws;          // MROWS*DIP bf16
    unsigned short* xc = zx + (size_t)MROWS * DIP;       // MROWS*CDIM bf16
    // total: 8192*(4240+2176)*2 B  ~= 100 MB

    // 1. zxbcdt = u @ in_proj_w^T  (bf16 out)
    {
        dim3 grid((DIP + 63) / 64, MROWS / 64);
        gemm_f32_bf16<<<grid, 256, 0, stream>>>(u, w_in, zx, MROWS, DIP, DM);
    }

    // 2. per-direction branch, out-proj accumulated per direction
    for (int dir = 0; dir < 2; dir++) {
        const float* cw  = dir ? conv_wb  : conv_w;
        const float* cb  = dir ? conv_bb  : conv_b;
        const float* dtb = dir ? dt_biasb : dt_bias;
        const float* Al  = dir ? A_b_log  : A_log;
        const float* Dd  = dir ? D_b      : Dp;

        conv_kernel<<<(MROWS * CDIM) / 256, 256, 0, stream>>>(zx, cw, cb, xc, dir);
        ssd_scan<<<BB * NH, 256, 0, stream>>>(xc, zx, dtb, Al, Dd, dir);
        branch_final<<<MROWS, 256, 0, stream>>>(xc, zx, norm_w, dir);

        dim3 grid(DM / 64, MROWS / 64);
        gemm_bf16A<<<grid, 256, 0, stream>>>(xc, CDIM, w_out, out,
                                             MROWS, DM, DI, dir, dir);
    }
}

// Round 3
// 2565.239 us; speedup vs baseline: 2.4878x; 2.4878x over previous
//
#include <hip/hip_runtime.h>
#include <hip/hip_bf16.h>
#include <math.h>

#define BB 2
#define LL 4096
#define DM 1024
#define DIP 4240
#define DI 2048
#define NH 16
#define HD 128
#define DS 64
#define CDIM 2176
#define MROWS (BB*LL)
#define Q 64
#define NC (LL/Q)
#define BH (BB*NH)

__device__ __forceinline__ float silu_f(float x) { return x / (1.f + expf(-x)); }
__device__ __forceinline__ float softplus_f(float x) {
    return fmaxf(x, 0.f) + log1pf(expf(-fabsf(x)));
}
__device__ __forceinline__ float bf2f(unsigned short u) {
    return __uint_as_float(((unsigned int)u) << 16);
}
__device__ __forceinline__ unsigned short f2bf(float f) {
    unsigned int x = __float_as_uint(f);
    return (unsigned short)((x + 0x7fff + ((x >> 16) & 1)) >> 16);
}

// ---------------------------------------------------------------------------
// C_bf16[M][N] = A_f32[M][K] * B_f32[N][K]^T
// ---------------------------------------------------------------------------
__global__ __launch_bounds__(256)
void gemm_f32_bf16(const float* __restrict__ A, const float* __restrict__ Bw,
                   unsigned short* __restrict__ C, int M, int N, int K)
{
    __shared__ float As[16][68];
    __shared__ float Bs[16][68];
    const int t  = threadIdx.x;
    const int tx = t & 15;
    const int ty = t >> 4;
    const int bm = blockIdx.y * 64;
    const int bn = blockIdx.x * 64;

    float acc[4][4] = {};
    const int r   = t >> 2;
    const int kk0 = (t & 3) * 4;

    for (int k0 = 0; k0 < K; k0 += 16) {
        {
            float4 av = *reinterpret_cast<const float4*>(&A[(size_t)(bm + r) * K + k0 + kk0]);
            As[kk0 + 0][r] = av.x; As[kk0 + 1][r] = av.y;
            As[kk0 + 2][r] = av.z; As[kk0 + 3][r] = av.w;
        }
        {
            int gn = bn + r;
            float4 bv = make_float4(0.f, 0.f, 0.f, 0.f);
            if (gn < N)
                bv = *reinterpret_cast<const float4*>(&Bw[(size_t)gn * K + k0 + kk0]);
            Bs[kk0 + 0][r] = bv.x; Bs[kk0 + 1][r] = bv.y;
            Bs[kk0 + 2][r] = bv.z; Bs[kk0 + 3][r] = bv.w;
        }
        __syncthreads();
        #pragma unroll
        for (int kk = 0; kk < 16; kk++) {
            float4 av = *reinterpret_cast<const float4*>(&As[kk][ty * 4]);
            float4 bv = *reinterpret_cast<const float4*>(&Bs[kk][tx * 4]);
            float a4[4] = {av.x, av.y, av.z, av.w};
            float b4[4] = {bv.x, bv.y, bv.z, bv.w};
            #pragma unroll
            for (int i = 0; i < 4; i++)
                #pragma unroll
                for (int j = 0; j < 4; j++)
                    acc[i][j] = fmaf(a4[i], b4[j], acc[i][j]);
        }
        __syncthreads();
    }

    #pragma unroll
    for (int i = 0; i < 4; i++) {
        int gm = bm + ty * 4 + i;
        #pragma unroll
        for (int j = 0; j < 4; j++) {
            int gn = bn + tx * 4 + j;
            if (gn < N) C[(size_t)gm * N + gn] = f2bf(acc[i][j]);
        }
    }
}

// ---------------------------------------------------------------------------
// out_f32[M][N] (acc)= A_bf16[M via lda, optional row-reverse] * B_f32[N][K]^T
// ---------------------------------------------------------------------------
__global__ __launch_bounds__(256)
void gemm_bf16A(const unsigned short* __restrict__ A, int lda,
                const float* __restrict__ Bw, float* __restrict__ C,
                int M, int N, int K, int rev, int accum)
{
    __shared__ float As[16][68];
    __shared__ float Bs[16][68];
    const int t  = threadIdx.x;
    const int tx = t & 15;
    const int ty = t >> 4;
    const int bm = blockIdx.y * 64;
    const int bn = blockIdx.x * 64;

    float acc[4][4] = {};
    const int r   = t >> 2;
    const int kk0 = (t & 3) * 4;

    int gm_load = bm + r;
    int src_row = gm_load;
    if (rev) {
        int rr = gm_load & (LL - 1);
        src_row = (gm_load & ~(LL - 1)) + (LL - 1 - rr);
    }

    for (int k0 = 0; k0 < K; k0 += 16) {
        {
            ushort4 uv = *reinterpret_cast<const ushort4*>(&A[(size_t)src_row * lda + k0 + kk0]);
            As[kk0 + 0][r] = bf2f(uv.x); As[kk0 + 1][r] = bf2f(uv.y);
            As[kk0 + 2][r] = bf2f(uv.z); As[kk0 + 3][r] = bf2f(uv.w);
        }
        {
            int gn = bn + r;
            float4 bv = make_float4(0.f, 0.f, 0.f, 0.f);
            if (gn < N)
                bv = *reinterpret_cast<const float4*>(&Bw[(size_t)gn * K + k0 + kk0]);
            Bs[kk0 + 0][r] = bv.x; Bs[kk0 + 1][r] = bv.y;
            Bs[kk0 + 2][r] = bv.z; Bs[kk0 + 3][r] = bv.w;
        }
        __syncthreads();
        #pragma unroll
        for (int kk = 0; kk < 16; kk++) {
            float4 av = *reinterpret_cast<const float4*>(&As[kk][ty * 4]);
            float4 bv = *reinterpret_cast<const float4*>(&Bs[kk][tx * 4]);
            float a4[4] = {av.x, av.y, av.z, av.w};
            float b4[4] = {bv.x, bv.y, bv.z, bv.w};
            #pragma unroll
            for (int i = 0; i < 4; i++)
                #pragma unroll
                for (int j = 0; j < 4; j++)
                    acc[i][j] = fmaf(a4[i], b4[j], acc[i][j]);
        }
        __syncthreads();
    }

    #pragma unroll
    for (int i = 0; i < 4; i++) {
        int gm = bm + ty * 4 + i;
        #pragma unroll
        for (int j = 0; j < 4; j++) {
            int gn = bn + tx * 4 + j;
            if (gn < N) {
                size_t idx = (size_t)gm * N + gn;
                if (accum) C[idx] += acc[i][j];
                else       C[idx]  = acc[i][j];
            }
        }
    }
}

// ---------------------------------------------------------------------------
// Depthwise causal conv (k=4) + SiLU, bf16; dir=1 reversed. Branch coords.
// ---------------------------------------------------------------------------
__global__ __launch_bounds__(256)
void conv_kernel(const unsigned short* __restrict__ zx, const float* __restrict__ cw,
                 const float* __restrict__ cb, unsigned short* __restrict__ xc, int dir)
{
    int idx = blockIdx.x * 256 + threadIdx.x;
    int c = idx % CDIM;
    int rb = idx / CDIM;
    int rr = rb & (LL - 1);
    int b  = rb >> 12;
    float acc = cb[c];
    #pragma unroll
    for (int k = 0; k < 4; k++) {
        int rsrc = rr - 3 + k;
        if (rsrc >= 0) {
            int l = dir ? (LL - 1 - rsrc) : rsrc;
            acc = fmaf(cw[c * 4 + k], bf2f(zx[(size_t)(b * LL + l) * DIP + DI + c]), acc);
        }
    }
    xc[(size_t)rb * CDIM + c] = f2bf(silu_f(acc));
}

// ---------------------------------------------------------------------------
// dt = softplus(raw + bias), layout dta[h][rb] (branch coords)
// ---------------------------------------------------------------------------
__global__ __launch_bounds__(256)
void dt_kernel(const unsigned short* __restrict__ zx, const float* __restrict__ dtb,
               float* __restrict__ dta, int dir)
{
    int idx = blockIdx.x * 256 + threadIdx.x;   // NH*MROWS
    int h  = idx >> 13;
    int rb = idx & (MROWS - 1);
    int rr = rb & (LL - 1);
    int b  = rb >> 12;
    int l  = dir ? (LL - 1 - rr) : rr;
    dta[idx] = softplus_f(bf2f(zx[(size_t)(b * LL + l) * DIP + (DIP - NH) + h]) + dtb[h]);
}

// ---------------------------------------------------------------------------
// Chunk states: S_c[p][n] = sum_j exp(A*(cum_{Q-1}-cum_j)) dt_j x_j[p] B_j[n]
// One block per (bh, chunk).  Also writes dtsum[bh][c].
// ---------------------------------------------------------------------------
__global__ __launch_bounds__(256)
void ssd_state(const unsigned short* __restrict__ xc, const float* __restrict__ dta,
               const float* __restrict__ A_log, unsigned short* __restrict__ hbuf,
               float* __restrict__ dtsum)
{
    int bh = blockIdx.x / NC;
    int c  = blockIdx.x % NC;
    int b = bh >> 4, h = bh & 15;
    float Ah = -expf(A_log[h]);
    int row0 = b * LL + c * Q;

    __shared__ unsigned short Xs[Q][132];
    __shared__ float wB[Q][68];
    __shared__ float dts_s[Q];
    __shared__ float cum_s[Q];

    const int tid = threadIdx.x;

    for (int idx = tid; idx < Q * 32; idx += 256) {
        int i = idx >> 5, p4 = (idx & 31) * 4;
        *reinterpret_cast<ushort4*>(&Xs[i][p4]) =
            *reinterpret_cast<const ushort4*>(&xc[(size_t)(row0 + i) * CDIM + h * HD + p4]);
    }
    if (tid < Q) dts_s[tid] = dta[h * MROWS + row0 + tid];
    __syncthreads();
    if (tid < Q) {
        float s = 0.f;
        for (int k = 0; k <= tid; k++) s += dts_s[k];
        cum_s[tid] = s;
    }
    __syncthreads();
    float cumlast = cum_s[Q - 1];
    if (tid == 0) dtsum[bh * NC + c] = cumlast;
    for (int idx = tid; idx < Q * DS; idx += 256) {
        int j = idx >> 6, n = idx & 63;
        float w = expf(Ah * (cumlast - cum_s[j])) * dts_s[j];
        wB[j][n] = w * bf2f(xc[(size_t)(row0 + j) * CDIM + DI + n]);
    }
    __syncthreads();

    int tn = tid & 7, tp = tid >> 3;
    float acc[4][8] = {};
    for (int j = 0; j < Q; j++) {
        float xv[4], wv[8];
        #pragma unroll
        for (int i = 0; i < 4; i++) xv[i] = bf2f(Xs[j][tp * 4 + i]);
        #pragma unroll
        for (int k = 0; k < 8; k++) wv[k] = wB[j][tn * 8 + k];
        #pragma unroll
        for (int i = 0; i < 4; i++)
            #pragma unroll
            for (int k = 0; k < 8; k++)
                acc[i][k] = fmaf(xv[i], wv[k], acc[i][k]);
    }
    size_t hb = ((size_t)c * BH + bh) * (HD * DS);
    #pragma unroll
    for (int i = 0; i < 4; i++) {
        unsigned short tmp[8];
        #pragma unroll
        for (int k = 0; k < 8; k++) tmp[k] = f2bf(acc[i][k]);
        size_t base = hb + (size_t)(tp * 4 + i) * DS + tn * 8;
        *reinterpret_cast<ushort4*>(&hbuf[base])     = *reinterpret_cast<ushort4*>(&tmp[0]);
        *reinterpret_cast<ushort4*>(&hbuf[base + 4]) = *reinterpret_cast<ushort4*>(&tmp[4]);
    }
}

// ---------------------------------------------------------------------------
// Inter-chunk recurrence (in place: slot c gets h_init BEFORE chunk c).
// ---------------------------------------------------------------------------
__global__ __launch_bounds__(256)
void ssd_interchunk(unsigned short* __restrict__ hbuf, const float* __restrict__ dtsum,
                    const float* __restrict__ A_log)
{
    int bh  = blockIdx.x >> 5;
    int seg = blockIdx.x & 31;
    int h = bh & 15;
    float Ah = -expf(A_log[h]);
    int off = seg * 256 + threadIdx.x;
    float hst = 0.f;
    for (int c = 0; c < NC; c++) {
        size_t idx = ((size_t)c * BH + bh) * (HD * DS) + off;
        float s = bf2f(hbuf[idx]);
        hbuf[idx] = f2bf(hst);
        hst = fmaf(hst, expf(Ah * dtsum[bh * NC + c]), s);
    }
}

// ---------------------------------------------------------------------------
// Intra-chunk output + inter contribution + D*x, written in place into xc.
// Y[i][p] = sum_j M_ij X[j][p] + P_i * sum_n C_i[n] h_init[p][n] + Dh*X[i][p]
// ---------------------------------------------------------------------------
__global__ __launch_bounds__(256)
void ssd_intra(unsigned short* __restrict__ xc, const unsigned short* __restrict__ hbuf,
               const float* __restrict__ dta, const float* __restrict__ A_log,
               const float* __restrict__ Dv)
{
    int bh = blockIdx.x / NC;
    int c  = blockIdx.x % NC;
    int b = bh >> 4, h = bh & 15;
    float Ah = -expf(A_log[h]);
    float Dh = Dv[h];
    int row0 = b * LL + c * Q;

    __shared__ unsigned short Xs[Q][132];
    __shared__ unsigned short Bs[Q][70];
    __shared__ unsigned short Cs[Q][70];
    __shared__ unsigned short Ms[Q][68];
    __shared__ unsigned short hsT[DS][132];
    __shared__ float dts_s[Q];
    __shared__ float cum_s[Q];

    const int tid = threadIdx.x;

    for (int idx = tid; idx < Q * 32; idx += 256) {
        int i = idx >> 5, p4 = (idx & 31) * 4;
        *reinterpret_cast<ushort4*>(&Xs[i][p4]) =
            *reinterpret_cast<const ushort4*>(&xc[(size_t)(row0 + i) * CDIM + h * HD + p4]);
    }
    for (int idx = tid; idx < Q * 32; idx += 256) {
        int j = idx >> 5, n2 = (idx & 31) * 2;
        *reinterpret_cast<ushort2*>(&Bs[j][n2]) =
            *reinterpret_cast<const ushort2*>(&xc[(size_t)(row0 + j) * CDIM + DI + n2]);
        *reinterpret_cast<ushort2*>(&Cs[j][n2]) =
            *reinterpret_cast<const ushort2*>(&xc[(size_t)(row0 + j) * CDIM + DI + DS + n2]);
    }
    {
        size_t hb = ((size_t)c * BH + bh) * (HD * DS);
        for (int idx = tid; idx < HD * DS; idx += 256) {
            int n = idx & 63, p = idx >> 6;
            hsT[n][p] = hbuf[hb + idx];
        }
    }
    if (tid < Q) dts_s[tid] = dta[h * MROWS + row0 + tid];
    __syncthreads();
    if (tid < Q) {
        float s = 0.f;
        for (int k = 0; k <= tid; k++) s += dts_s[k];
        cum_s[tid] = s;
    }
    __syncthreads();

    // G = C B^T -> masked, weighted -> Ms (bf16)
    {
        int ti = tid >> 4, tj = tid & 15;
        float acc[4][4] = {};
        for (int n = 0; n < DS; n++) {
            float cv[4], bv[4];
            #pragma unroll
            for (int i = 0; i < 4; i++) cv[i] = bf2f(Cs[ti * 4 + i][n]);
            #pragma unroll
            for (int j = 0; j < 4; j++) bv[j] = bf2f(Bs[tj * 4 + j][n]);
            #pragma unroll
            for (int i = 0; i < 4; i++)
                #pragma unroll
                for (int j = 0; j < 4; j++)
                    acc[i][j] = fmaf(cv[i], bv[j], acc[i][j]);
        }
        #pragma unroll
        for (int ii = 0; ii < 4; ii++) {
            int i = ti * 4 + ii;
            #pragma unroll
            for (int jj = 0; jj < 4; jj++) {
                int j = tj * 4 + jj;
                float w = (j <= i) ? expf(Ah * (cum_s[i] - cum_s[j])) * dts_s[j] : 0.f;
                Ms[i][j] = f2bf(acc[ii][jj] * w);
            }
        }
    }
    __syncthreads();

    {
        int ti = tid >> 4, tp = tid & 15;
        float acc[4][8] = {};
        float acc2[4][8] = {};
        for (int j = 0; j < Q; j++) {
            float mv[4], xv[8];
            #pragma unroll
            for (int ii = 0; ii < 4; ii++) mv[ii] = bf2f(Ms[ti * 4 + ii][j]);
            #pragma unroll
            for (int k = 0; k < 8; k++) xv[k] = bf2f(Xs[j][tp * 8 + k]);
            #pragma unroll
            for (int ii = 0; ii < 4; ii++)
                #pragma unroll
                for (int k = 0; k < 8; k++)
                    acc[ii][k] = fmaf(mv[ii], xv[k], acc[ii][k]);
        }
        for (int n = 0; n < DS; n++) {
            float cv[4], hv[8];
            #pragma unroll
            for (int ii = 0; ii < 4; ii++) cv[ii] = bf2f(Cs[ti * 4 + ii][n]);
            #pragma unroll
            for (int k = 0; k < 8; k++) hv[k] = bf2f(hsT[n][tp * 8 + k]);
            #pragma unroll
            for (int ii = 0; ii < 4; ii++)
                #pragma unroll
                for (int k = 0; k < 8; k++)
                    acc2[ii][k] = fmaf(cv[ii], hv[k], acc2[ii][k]);
        }
        #pragma unroll
        for (int ii = 0; ii < 4; ii++) {
            int i = ti * 4 + ii;
            float Pi = expf(Ah * cum_s[i]);
            unsigned short tmp[8];
            #pragma unroll
            for (int k = 0; k < 8; k++) {
                float xval = bf2f(Xs[i][tp * 8 + k]);
                tmp[k] = f2bf(fmaf(Dh, xval, fmaf(Pi, acc2[ii][k], acc[ii][k])));
            }
            size_t base = (size_t)(row0 + i) * CDIM + h * HD + tp * 8;
            *reinterpret_cast<ushort4*>(&xc[base])     = *reinterpret_cast<ushort4*>(&tmp[0]);
            *reinterpret_cast<ushort4*>(&xc[base + 4]) = *reinterpret_cast<ushort4*>(&tmp[4]);
        }
    }
}

// ---------------------------------------------------------------------------
// Gated RMSNorm, in place over the x-columns of xc.
// ---------------------------------------------------------------------------
__global__ __launch_bounds__(256)
void branch_final(unsigned short* __restrict__ xc, const unsigned short* __restrict__ zx,
                  const float* __restrict__ nw, int dir)
{
    int row = blockIdx.x;
    int rr = row & (LL - 1);
    int b  = row >> 12;
    int l  = dir ? (LL - 1 - rr) : rr;

    unsigned short* yrow = xc + (size_t)row * CDIM;
    const unsigned short* zrow = zx + (size_t)(b * LL + l) * DIP;

    float v[8];
    float ss = 0.f;
    #pragma unroll
    for (int i = 0; i < 8; i++) {
        int c = threadIdx.x + i * 256;
        float val = bf2f(yrow[c]) * silu_f(bf2f(zrow[c]));
        v[i] = val;
        ss = fmaf(val, val, ss);
    }
    #pragma unroll
    for (int o = 32; o > 0; o >>= 1) ss += __shfl_down(ss, o);
    __shared__ float red[4];
    if ((threadIdx.x & 63) == 0) red[threadIdx.x >> 6] = ss;
    __syncthreads();
    ss = red[0] + red[1] + red[2] + red[3];
    float scale = rsqrtf(ss * (1.f / DI) + 1e-5f);

    #pragma unroll
    for (int i = 0; i < 8; i++) {
        int c = threadIdx.x + i * 256;
        yrow[c] = f2bf(v[i] * scale * nw[c]);
    }
}

// ---------------------------------------------------------------------------
extern "C" void kernel_launch(void* const* d_in, const int* in_sizes, int n_in,
                              void* d_out, int out_size, void* d_ws, size_t ws_size,
                              hipStream_t stream)
{
    const float* u       = (const float*)d_in[0];
    const float* w_in    = (const float*)d_in[1];
    const float* conv_w  = (const float*)d_in[2];
    const float* conv_b  = (const float*)d_in[3];
    const float* conv_wb = (const float*)d_in[4];
    const float* conv_bb = (const float*)d_in[5];
    const float* dt_bias  = (const float*)d_in[6];
    const float* dt_biasb = (const float*)d_in[7];
    const float* A_log   = (const float*)d_in[8];
    const float* A_b_log = (const float*)d_in[9];
    const float* Dp      = (const float*)d_in[10];
    const float* D_b     = (const float*)d_in[11];
    const float* norm_w  = (const float*)d_in[12];
    const float* w_out   = (const float*)d_in[13];
    float* out = (float*)d_out;

    unsigned short* zx   = (unsigned short*)d_ws;              // MROWS*DIP
    unsigned short* xc   = zx + (size_t)MROWS * DIP;           // MROWS*CDIM
    unsigned short* hbuf = xc + (size_t)MROWS * CDIM;          // NC*BH*HD*DS
    float* dta   = (float*)(hbuf + (size_t)NC * BH * HD * DS); // NH*MROWS
    float* dtsum = dta + (size_t)NH * MROWS;                   // BH*NC

    // 1. zxbcdt = u @ in_proj_w^T  (bf16 out)
    {
        dim3 grid((DIP + 63) / 64, MROWS / 64);
        gemm_f32_bf16<<<grid, 256, 0, stream>>>(u, w_in, zx, MROWS, DIP, DM);
    }

    // 2. per-direction branch; out-proj accumulated per direction
    for (int dir = 0; dir < 2; dir++) {
        const float* cw  = dir ? conv_wb  : conv_w;
        const float* cb  = dir ? conv_bb  : conv_b;
        const float* dtb = dir ? dt_biasb : dt_bias;
        const float* Al  = dir ? A_b_log  : A_log;
        const float* Dd  = dir ? D_b      : Dp;

        conv_kernel<<<(MROWS * CDIM) / 256, 256, 0, stream>>>(zx, cw, cb, xc, dir);
        dt_kernel<<<(NH * MROWS) / 256, 256, 0, stream>>>(zx, dtb, dta, dir);
        ssd_state<<<BH * NC, 256, 0, stream>>>(xc, dta, Al, hbuf, dtsum);
        ssd_interchunk<<<BH * 32, 256, 0, stream>>>(hbuf, dtsum, Al);
        ssd_intra<<<BH * NC, 256, 0, stream>>>(xc, hbuf, dta, Al, Dd);
        branch_final<<<MROWS, 256, 0, stream>>>(xc, zx, norm_w, dir);

        dim3 grid(DM / 64, MROWS / 64);
        gemm_bf16A<<<grid, 256, 0, stream>>>(xc, CDIM, w_out, out,
                                             MROWS, DM, DI, dir, dir);
    }
}

// Round 4
// 906.587 us; speedup vs baseline: 7.0394x; 2.8296x over previous
//
#include <hip/hip_runtime.h>
#include <hip/hip_bf16.h>
#include <math.h>

#define BB 2
#define LL 4096
#define DM 1024
#define DIP 4240
#define DIPP 4352          // padded N for in-proj (34*128)
#define DI 2048
#define NH 16
#define HD 128
#define DS 64
#define CDIM 2176
#define MROWS (BB*LL)
#define Q 64
#define NC (LL/Q)
#define BH (BB*NH)

typedef __attribute__((ext_vector_type(8))) short bf16x8;
typedef __attribute__((ext_vector_type(4))) float f32x4;

__device__ __forceinline__ float silu_f(float x) { return x / (1.f + expf(-x)); }
__device__ __forceinline__ float softplus_f(float x) {
    return fmaxf(x, 0.f) + log1pf(expf(-fabsf(x)));
}
__device__ __forceinline__ float bf2f(unsigned short u) {
    return __uint_as_float(((unsigned int)u) << 16);
}
__device__ __forceinline__ unsigned short f2bf(float f) {
    unsigned int x = __float_as_uint(f);
    return (unsigned short)((x + 0x7fff + ((x >> 16) & 1)) >> 16);
}
__device__ __forceinline__ void gll16(const void* g, void* l) {
    __builtin_amdgcn_global_load_lds(
        (const __attribute__((address_space(1))) void*)g,
        (__attribute__((address_space(3))) void*)l,
        16, 0, 0);
}

// ---------------------------------------------------------------------------
// fp32 -> bf16 conversion with optional row padding (pad rows = 0)
// ---------------------------------------------------------------------------
__global__ __launch_bounds__(256)
void cvt_pad(const float* __restrict__ in, unsigned short* __restrict__ out,
             int rows_real, int rows_pad, int cols)
{
    int idx = blockIdx.x * 256 + threadIdx.x;
    int cols4 = cols >> 2;
    int total = rows_pad * cols4;
    if (idx >= total) return;
    int row = idx / cols4;
    int c4 = (idx - row * cols4) * 4;
    ushort4 o;
    if (row < rows_real) {
        float4 v = *reinterpret_cast<const float4*>(&in[(size_t)row * cols + c4]);
        o.x = f2bf(v.x); o.y = f2bf(v.y); o.z = f2bf(v.z); o.w = f2bf(v.w);
    } else {
        o = make_ushort4(0, 0, 0, 0);
    }
    *reinterpret_cast<ushort4*>(&out[(size_t)row * cols + c4]) = o;
}

// ---------------------------------------------------------------------------
// MFMA bf16 GEMM, m97 structure: 128x128 tile, 4 waves (2x2), BK=32,
// global_load_lds staging, 16x mfma_f32_16x16x32_bf16 per K-step.
//   C[M][N](ldc) = A[M][K](lda, optional row-reverse) * B[N][K]^T
// ATYPE: 0 = A fp32 (reg-staged + converted), 1 = A bf16 (global_load_lds)
// OMODE: 0 = write bf16 bounded by Nreal, 1 = write f32, 2 = accumulate f32
// M,N multiples of 128 (grid exact), K multiple of 32.
// ---------------------------------------------------------------------------
template<int ATYPE, int OMODE>
__global__ __launch_bounds__(256)
void gemm_mfma(const void* __restrict__ Ap, int lda, int rev,
               const unsigned short* __restrict__ Bp, int K,
               void* __restrict__ Cp, int ldc, int Nreal)
{
    __shared__ alignas(16) unsigned short As[128 * 32];
    __shared__ alignas(16) unsigned short Bs[128 * 32];

    const int t = threadIdx.x;
    const int l = t & 63;
    const int bm = blockIdx.y * 128, bn = blockIdx.x * 128;
    const int wm = ((t >> 6) >> 1) * 64, wn = ((t >> 6) & 1) * 64;

    f32x4 acc[4][4];
    #pragma unroll
    for (int i = 0; i < 4; i++)
        #pragma unroll
        for (int j = 0; j < 4; j++)
            acc[i][j] = (f32x4){0.f, 0.f, 0.f, 0.f};

    for (int k0 = 0; k0 < K; k0 += 32) {
        // ---- stage A tile [128][32] ----
        if (ATYPE == 0) {
            #pragma unroll
            for (int i = 0; i < 2; i++) {
                int c = i * 256 + t;
                int row = c >> 2, ke = (c & 3) * 8;
                const float* src = (const float*)Ap + (size_t)(bm + row) * lda + k0 + ke;
                float4 v0 = *reinterpret_cast<const float4*>(src);
                float4 v1 = *reinterpret_cast<const float4*>(src + 4);
                unsigned short tmp[8];
                tmp[0] = f2bf(v0.x); tmp[1] = f2bf(v0.y);
                tmp[2] = f2bf(v0.z); tmp[3] = f2bf(v0.w);
                tmp[4] = f2bf(v1.x); tmp[5] = f2bf(v1.y);
                tmp[6] = f2bf(v1.z); tmp[7] = f2bf(v1.w);
                *reinterpret_cast<uint4*>(&As[c * 8]) = *reinterpret_cast<const uint4*>(tmp);
            }
        } else {
            #pragma unroll
            for (int i = 0; i < 2; i++) {
                int c = i * 256 + t;
                int row = c >> 2, ke = (c & 3) * 8;
                int grow = bm + row;
                if (rev) { int rr = grow & (LL - 1); grow = (grow & ~(LL - 1)) + (LL - 1 - rr); }
                const unsigned short* src = (const unsigned short*)Ap + (size_t)grow * lda + k0 + ke;
                gll16(src, (char*)&As[0] + c * 16);
            }
        }
        // ---- stage B tile [128][32] ----
        #pragma unroll
        for (int i = 0; i < 2; i++) {
            int c = i * 256 + t;
            int row = c >> 2, ke = (c & 3) * 8;
            gll16(Bp + (size_t)(bn + row) * K + k0 + ke, (char*)&Bs[0] + c * 16);
        }
        __syncthreads();

        // ---- compute: 4x4 MFMA over the K=32 step ----
        bf16x8 af[4], bfr[4];
        #pragma unroll
        for (int mi = 0; mi < 4; mi++)
            af[mi] = *reinterpret_cast<const bf16x8*>(
                &As[(wm + mi * 16 + (l & 15)) * 32 + (l >> 4) * 8]);
        #pragma unroll
        for (int nj = 0; nj < 4; nj++)
            bfr[nj] = *reinterpret_cast<const bf16x8*>(
                &Bs[(wn + nj * 16 + (l & 15)) * 32 + (l >> 4) * 8]);
        #pragma unroll
        for (int mi = 0; mi < 4; mi++)
            #pragma unroll
            for (int nj = 0; nj < 4; nj++)
                acc[mi][nj] = __builtin_amdgcn_mfma_f32_16x16x32_bf16(
                    af[mi], bfr[nj], acc[mi][nj], 0, 0, 0);
        __syncthreads();
    }

    // ---- epilogue: C/D layout col=l&15, row=(l>>4)*4+r ----
    const int col_l = l & 15, rgrp = (l >> 4) * 4;
    #pragma unroll
    for (int mi = 0; mi < 4; mi++) {
        #pragma unroll
        for (int r = 0; r < 4; r++) {
            int gm = bm + wm + mi * 16 + rgrp + r;
            #pragma unroll
            for (int nj = 0; nj < 4; nj++) {
                int gn = bn + wn + nj * 16 + col_l;
                float v = acc[mi][nj][r];
                if (OMODE == 0) {
                    if (gn < Nreal)
                        ((unsigned short*)Cp)[(size_t)gm * ldc + gn] = f2bf(v);
                } else if (OMODE == 1) {
                    ((float*)Cp)[(size_t)gm * ldc + gn] = v;
                } else {
                    ((float*)Cp)[(size_t)gm * ldc + gn] += v;
                }
            }
        }
    }
}

// ---------------------------------------------------------------------------
// Depthwise causal conv (k=4) + SiLU, bf16; dir=1 reversed. Branch coords.
// ---------------------------------------------------------------------------
__global__ __launch_bounds__(256)
void conv_kernel(const unsigned short* __restrict__ zx, const float* __restrict__ cw,
                 const float* __restrict__ cb, unsigned short* __restrict__ xc, int dir)
{
    int idx = blockIdx.x * 256 + threadIdx.x;
    int c = idx % CDIM;
    int rb = idx / CDIM;
    int rr = rb & (LL - 1);
    int b  = rb >> 12;
    float acc = cb[c];
    #pragma unroll
    for (int k = 0; k < 4; k++) {
        int rsrc = rr - 3 + k;
        if (rsrc >= 0) {
            int l = dir ? (LL - 1 - rsrc) : rsrc;
            acc = fmaf(cw[c * 4 + k], bf2f(zx[(size_t)(b * LL + l) * DIP + DI + c]), acc);
        }
    }
    xc[(size_t)rb * CDIM + c] = f2bf(silu_f(acc));
}

// ---------------------------------------------------------------------------
// dt = softplus(raw + bias), layout dta[h][rb] (branch coords)
// ---------------------------------------------------------------------------
__global__ __launch_bounds__(256)
void dt_kernel(const unsigned short* __restrict__ zx, const float* __restrict__ dtb,
               float* __restrict__ dta, int dir)
{
    int idx = blockIdx.x * 256 + threadIdx.x;   // NH*MROWS
    int h  = idx >> 13;
    int rb = idx & (MROWS - 1);
    int rr = rb & (LL - 1);
    int b  = rb >> 12;
    int l  = dir ? (LL - 1 - rr) : rr;
    dta[idx] = softplus_f(bf2f(zx[(size_t)(b * LL + l) * DIP + (DIP - NH) + h]) + dtb[h]);
}

// ---------------------------------------------------------------------------
// Chunk states: S_c[p][n] = sum_j exp(A*(cum_{Q-1}-cum_j)) dt_j x_j[p] B_j[n]
// ---------------------------------------------------------------------------
__global__ __launch_bounds__(256)
void ssd_state(const unsigned short* __restrict__ xc, const float* __restrict__ dta,
               const float* __restrict__ A_log, unsigned short* __restrict__ hbuf,
               float* __restrict__ dtsum)
{
    int bh = blockIdx.x / NC;
    int c  = blockIdx.x % NC;
    int b = bh >> 4, h = bh & 15;
    float Ah = -expf(A_log[h]);
    int row0 = b * LL + c * Q;

    __shared__ unsigned short Xs[Q][132];
    __shared__ float wB[Q][68];
    __shared__ float dts_s[Q];
    __shared__ float cum_s[Q];

    const int tid = threadIdx.x;

    for (int idx = tid; idx < Q * 32; idx += 256) {
        int i = idx >> 5, p4 = (idx & 31) * 4;
        *reinterpret_cast<ushort4*>(&Xs[i][p4]) =
            *reinterpret_cast<const ushort4*>(&xc[(size_t)(row0 + i) * CDIM + h * HD + p4]);
    }
    if (tid < Q) dts_s[tid] = dta[h * MROWS + row0 + tid];
    __syncthreads();
    if (tid < Q) {
        float s = 0.f;
        for (int k = 0; k <= tid; k++) s += dts_s[k];
        cum_s[tid] = s;
    }
    __syncthreads();
    float cumlast = cum_s[Q - 1];
    if (tid == 0) dtsum[bh * NC + c] = cumlast;
    for (int idx = tid; idx < Q * DS; idx += 256) {
        int j = idx >> 6, n = idx & 63;
        float w = expf(Ah * (cumlast - cum_s[j])) * dts_s[j];
        wB[j][n] = w * bf2f(xc[(size_t)(row0 + j) * CDIM + DI + n]);
    }
    __syncthreads();

    int tn = tid & 7, tp = tid >> 3;
    float acc[4][8] = {};
    for (int j = 0; j < Q; j++) {
        float xv[4], wv[8];
        #pragma unroll
        for (int i = 0; i < 4; i++) xv[i] = bf2f(Xs[j][tp * 4 + i]);
        #pragma unroll
        for (int k = 0; k < 8; k++) wv[k] = wB[j][tn * 8 + k];
        #pragma unroll
        for (int i = 0; i < 4; i++)
            #pragma unroll
            for (int k = 0; k < 8; k++)
                acc[i][k] = fmaf(xv[i], wv[k], acc[i][k]);
    }
    size_t hb = ((size_t)c * BH + bh) * (HD * DS);
    #pragma unroll
    for (int i = 0; i < 4; i++) {
        unsigned short tmp[8];
        #pragma unroll
        for (int k = 0; k < 8; k++) tmp[k] = f2bf(acc[i][k]);
        size_t base = hb + (size_t)(tp * 4 + i) * DS + tn * 8;
        *reinterpret_cast<ushort4*>(&hbuf[base])     = *reinterpret_cast<ushort4*>(&tmp[0]);
        *reinterpret_cast<ushort4*>(&hbuf[base + 4]) = *reinterpret_cast<ushort4*>(&tmp[4]);
    }
}

// ---------------------------------------------------------------------------
// Inter-chunk recurrence (in place: slot c gets h_init BEFORE chunk c).
// ---------------------------------------------------------------------------
__global__ __launch_bounds__(256)
void ssd_interchunk(unsigned short* __restrict__ hbuf, const float* __restrict__ dtsum,
                    const float* __restrict__ A_log)
{
    int bh  = blockIdx.x >> 5;
    int seg = blockIdx.x & 31;
    int h = bh & 15;
    float Ah = -expf(A_log[h]);
    int off = seg * 256 + threadIdx.x;
    float hst = 0.f;
    for (int c = 0; c < NC; c++) {
        size_t idx = ((size_t)c * BH + bh) * (HD * DS) + off;
        float s = bf2f(hbuf[idx]);
        hbuf[idx] = f2bf(hst);
        hst = fmaf(hst, expf(Ah * dtsum[bh * NC + c]), s);
    }
}

// ---------------------------------------------------------------------------
// Intra-chunk output + inter contribution + D*x, written in place into xc.
// ---------------------------------------------------------------------------
__global__ __launch_bounds__(256)
void ssd_intra(unsigned short* __restrict__ xc, const unsigned short* __restrict__ hbuf,
               const float* __restrict__ dta, const float* __restrict__ A_log,
               const float* __restrict__ Dv)
{
    int bh = blockIdx.x / NC;
    int c  = blockIdx.x % NC;
    int b = bh >> 4, h = bh & 15;
    float Ah = -expf(A_log[h]);
    float Dh = Dv[h];
    int row0 = b * LL + c * Q;

    __shared__ unsigned short Xs[Q][132];
    __shared__ unsigned short Bs[Q][70];
    __shared__ unsigned short Cs[Q][70];
    __shared__ unsigned short Ms[Q][68];
    __shared__ unsigned short hsT[DS][132];
    __shared__ float dts_s[Q];
    __shared__ float cum_s[Q];

    const int tid = threadIdx.x;

    for (int idx = tid; idx < Q * 32; idx += 256) {
        int i = idx >> 5, p4 = (idx & 31) * 4;
        *reinterpret_cast<ushort4*>(&Xs[i][p4]) =
            *reinterpret_cast<const ushort4*>(&xc[(size_t)(row0 + i) * CDIM + h * HD + p4]);
    }
    for (int idx = tid; idx < Q * 32; idx += 256) {
        int j = idx >> 5, n2 = (idx & 31) * 2;
        *reinterpret_cast<ushort2*>(&Bs[j][n2]) =
            *reinterpret_cast<const ushort2*>(&xc[(size_t)(row0 + j) * CDIM + DI + n2]);
        *reinterpret_cast<ushort2*>(&Cs[j][n2]) =
            *reinterpret_cast<const ushort2*>(&xc[(size_t)(row0 + j) * CDIM + DI + DS + n2]);
    }
    {
        size_t hb = ((size_t)c * BH + bh) * (HD * DS);
        for (int idx = tid; idx < HD * DS; idx += 256) {
            int n = idx & 63, p = idx >> 6;
            hsT[n][p] = hbuf[hb + idx];
        }
    }
    if (tid < Q) dts_s[tid] = dta[h * MROWS + row0 + tid];
    __syncthreads();
    if (tid < Q) {
        float s = 0.f;
        for (int k = 0; k <= tid; k++) s += dts_s[k];
        cum_s[tid] = s;
    }
    __syncthreads();

    // G = C B^T -> masked, weighted -> Ms (bf16)
    {
        int ti = tid >> 4, tj = tid & 15;
        float acc[4][4] = {};
        for (int n = 0; n < DS; n++) {
            float cv[4], bv[4];
            #pragma unroll
            for (int i = 0; i < 4; i++) cv[i] = bf2f(Cs[ti * 4 + i][n]);
            #pragma unroll
            for (int j = 0; j < 4; j++) bv[j] = bf2f(Bs[tj * 4 + j][n]);
            #pragma unroll
            for (int i = 0; i < 4; i++)
                #pragma unroll
                for (int j = 0; j < 4; j++)
                    acc[i][j] = fmaf(cv[i], bv[j], acc[i][j]);
        }
        #pragma unroll
        for (int ii = 0; ii < 4; ii++) {
            int i = ti * 4 + ii;
            #pragma unroll
            for (int jj = 0; jj < 4; jj++) {
                int j = tj * 4 + jj;
                float w = (j <= i) ? expf(Ah * (cum_s[i] - cum_s[j])) * dts_s[j] : 0.f;
                Ms[i][j] = f2bf(acc[ii][jj] * w);
            }
        }
    }
    __syncthreads();

    {
        int ti = tid >> 4, tp = tid & 15;
        float acc[4][8] = {};
        float acc2[4][8] = {};
        for (int j = 0; j < Q; j++) {
            float mv[4], xv[8];
            #pragma unroll
            for (int ii = 0; ii < 4; ii++) mv[ii] = bf2f(Ms[ti * 4 + ii][j]);
            #pragma unroll
            for (int k = 0; k < 8; k++) xv[k] = bf2f(Xs[j][tp * 8 + k]);
            #pragma unroll
            for (int ii = 0; ii < 4; ii++)
                #pragma unroll
                for (int k = 0; k < 8; k++)
                    acc[ii][k] = fmaf(mv[ii], xv[k], acc[ii][k]);
        }
        for (int n = 0; n < DS; n++) {
            float cv[4], hv[8];
            #pragma unroll
            for (int ii = 0; ii < 4; ii++) cv[ii] = bf2f(Cs[ti * 4 + ii][n]);
            #pragma unroll
            for (int k = 0; k < 8; k++) hv[k] = bf2f(hsT[n][tp * 8 + k]);
            #pragma unroll
            for (int ii = 0; ii < 4; ii++)
                #pragma unroll
                for (int k = 0; k < 8; k++)
                    acc2[ii][k] = fmaf(cv[ii], hv[k], acc2[ii][k]);
        }
        #pragma unroll
        for (int ii = 0; ii < 4; ii++) {
            int i = ti * 4 + ii;
            float Pi = expf(Ah * cum_s[i]);
            unsigned short tmp[8];
            #pragma unroll
            for (int k = 0; k < 8; k++) {
                float xval = bf2f(Xs[i][tp * 8 + k]);
                tmp[k] = f2bf(fmaf(Dh, xval, fmaf(Pi, acc2[ii][k], acc[ii][k])));
            }
            size_t base = (size_t)(row0 + i) * CDIM + h * HD + tp * 8;
            *reinterpret_cast<ushort4*>(&xc[base])     = *reinterpret_cast<ushort4*>(&tmp[0]);
            *reinterpret_cast<ushort4*>(&xc[base + 4]) = *reinterpret_cast<ushort4*>(&tmp[4]);
        }
    }
}

// ---------------------------------------------------------------------------
// Gated RMSNorm, in place over the x-columns of xc.
// ---------------------------------------------------------------------------
__global__ __launch_bounds__(256)
void branch_final(unsigned short* __restrict__ xc, const unsigned short* __restrict__ zx,
                  const float* __restrict__ nw, int dir)
{
    int row = blockIdx.x;
    int rr = row & (LL - 1);
    int b  = row >> 12;
    int l  = dir ? (LL - 1 - rr) : rr;

    unsigned short* yrow = xc + (size_t)row * CDIM;
    const unsigned short* zrow = zx + (size_t)(b * LL + l) * DIP;

    float v[8];
    float ss = 0.f;
    #pragma unroll
    for (int i = 0; i < 8; i++) {
        int c = threadIdx.x + i * 256;
        float val = bf2f(yrow[c]) * silu_f(bf2f(zrow[c]));
        v[i] = val;
        ss = fmaf(val, val, ss);
    }
    #pragma unroll
    for (int o = 32; o > 0; o >>= 1) ss += __shfl_down(ss, o);
    __shared__ float red[4];
    if ((threadIdx.x & 63) == 0) red[threadIdx.x >> 6] = ss;
    __syncthreads();
    ss = red[0] + red[1] + red[2] + red[3];
    float scale = rsqrtf(ss * (1.f / DI) + 1e-5f);

    #pragma unroll
    for (int i = 0; i < 8; i++) {
        int c = threadIdx.x + i * 256;
        yrow[c] = f2bf(v[i] * scale * nw[c]);
    }
}

// ---------------------------------------------------------------------------
extern "C" void kernel_launch(void* const* d_in, const int* in_sizes, int n_in,
                              void* d_out, int out_size, void* d_ws, size_t ws_size,
                              hipStream_t stream)
{
    const float* u       = (const float*)d_in[0];
    const float* w_in    = (const float*)d_in[1];
    const float* conv_w  = (const float*)d_in[2];
    const float* conv_b  = (const float*)d_in[3];
    const float* conv_wb = (const float*)d_in[4];
    const float* conv_bb = (const float*)d_in[5];
    const float* dt_bias  = (const float*)d_in[6];
    const float* dt_biasb = (const float*)d_in[7];
    const float* A_log   = (const float*)d_in[8];
    const float* A_b_log = (const float*)d_in[9];
    const float* Dp      = (const float*)d_in[10];
    const float* D_b     = (const float*)d_in[11];
    const float* norm_w  = (const float*)d_in[12];
    const float* w_out   = (const float*)d_in[13];
    float* out = (float*)d_out;

    unsigned short* zx   = (unsigned short*)d_ws;              // MROWS*DIP
    unsigned short* xc   = zx + (size_t)MROWS * DIP;           // MROWS*CDIM
    unsigned short* hbuf = xc + (size_t)MROWS * CDIM;          // NC*BH*HD*DS
    float* dta   = (float*)(hbuf + (size_t)NC * BH * HD * DS); // NH*MROWS
    float* dtsum = dta + (size_t)NH * MROWS;                   // BH*NC
    unsigned short* wbin  = (unsigned short*)(dtsum + BH * NC); // DIPP*DM
    unsigned short* wbout = wbin + (size_t)DIPP * DM;           // DM*DI
    // total ~152.3 MB

    // 0. convert weights to bf16 (in_proj padded to DIPP rows)
    cvt_pad<<<(DIPP * (DM / 4) + 255) / 256, 256, 0, stream>>>(w_in, wbin, DIP, DIPP, DM);
    cvt_pad<<<(DM * (DI / 4) + 255) / 256, 256, 0, stream>>>(w_out, wbout, DM, DM, DI);

    // 1. zxbcdt = u @ in_proj_w^T  (bf16 out, MFMA)
    {
        dim3 grid(DIPP / 128, MROWS / 128);
        gemm_mfma<0, 0><<<grid, 256, 0, stream>>>(u, DM, 0, wbin, DM, zx, DIP, DIP);
    }

    // 2. per-direction branch; out-proj accumulated per direction
    for (int dir = 0; dir < 2; dir++) {
        const float* cw  = dir ? conv_wb  : conv_w;
        const float* cb  = dir ? conv_bb  : conv_b;
        const float* dtb = dir ? dt_biasb : dt_bias;
        const float* Al  = dir ? A_b_log  : A_log;
        const float* Dd  = dir ? D_b      : Dp;

        conv_kernel<<<(MROWS * CDIM) / 256, 256, 0, stream>>>(zx, cw, cb, xc, dir);
        dt_kernel<<<(NH * MROWS) / 256, 256, 0, stream>>>(zx, dtb, dta, dir);
        ssd_state<<<BH * NC, 256, 0, stream>>>(xc, dta, Al, hbuf, dtsum);
        ssd_interchunk<<<BH * 32, 256, 0, stream>>>(hbuf, dtsum, Al);
        ssd_intra<<<BH * NC, 256, 0, stream>>>(xc, hbuf, dta, Al, Dd);
        branch_final<<<MROWS, 256, 0, stream>>>(xc, zx, norm_w, dir);

        // 3. out (+)= y_branch @ out_proj_w^T  (MFMA, row-reversed A for dir=1)
        dim3 grid(DM / 128, MROWS / 128);
        if (dir == 0)
            gemm_mfma<1, 1><<<grid, 256, 0, stream>>>(xc, CDIM, 0, wbout, DI, out, DM, DM);
        else
            gemm_mfma<1, 2><<<grid, 256, 0, stream>>>(xc, CDIM, 1, wbout, DI, out, DM, DM);
    }
}

// Round 5
// 898.190 us; speedup vs baseline: 7.1052x; 1.0093x over previous
//
#include <hip/hip_runtime.h>
#include <hip/hip_bf16.h>
#include <math.h>

#define BB 2
#define LL 4096
#define DM 1024
#define DIP 4240
#define DIPP 4352          // padded N for in-proj (34*128)
#define DI 2048
#define NH 16
#define HD 128
#define DS 64
#define CDIM 2176
#define MROWS (BB*LL)
#define Q 64
#define NC (LL/Q)
#define BH (BB*NH)

typedef __attribute__((ext_vector_type(8))) short bf16x8;
typedef __attribute__((ext_vector_type(4))) float f32x4;

__device__ __forceinline__ float silu_f(float x) { return x / (1.f + expf(-x)); }
__device__ __forceinline__ float softplus_f(float x) {
    return fmaxf(x, 0.f) + log1pf(expf(-fabsf(x)));
}
__device__ __forceinline__ float bf2f(unsigned short u) {
    return __uint_as_float(((unsigned int)u) << 16);
}
__device__ __forceinline__ unsigned short f2bf(float f) {
    unsigned int x = __float_as_uint(f);
    return (unsigned short)((x + 0x7fff + ((x >> 16) & 1)) >> 16);
}
__device__ __forceinline__ void gll16(const void* g, void* l) {
    __builtin_amdgcn_global_load_lds(
        (const __attribute__((address_space(1))) void*)g,
        (__attribute__((address_space(3))) void*)l,
        16, 0, 0);
}

// ---------------------------------------------------------------------------
// fp32 -> bf16 weight conversion with optional row padding (pad rows = 0)
// ---------------------------------------------------------------------------
__global__ __launch_bounds__(256)
void cvt_pad(const float* __restrict__ in, unsigned short* __restrict__ out,
             int rows_real, int rows_pad, int cols)
{
    int idx = blockIdx.x * 256 + threadIdx.x;
    int cols4 = cols >> 2;
    int total = rows_pad * cols4;
    if (idx >= total) return;
    int row = idx / cols4;
    int c4 = (idx - row * cols4) * 4;
    ushort4 o;
    if (row < rows_real) {
        float4 v = *reinterpret_cast<const float4*>(&in[(size_t)row * cols + c4]);
        o.x = f2bf(v.x); o.y = f2bf(v.y); o.z = f2bf(v.z); o.w = f2bf(v.w);
    } else {
        o = make_ushort4(0, 0, 0, 0);
    }
    *reinterpret_cast<ushort4*>(&out[(size_t)row * cols + c4]) = o;
}

// ---------------------------------------------------------------------------
// u fp32 -> bf16 (contiguous, 8 elems/thread)
// ---------------------------------------------------------------------------
__global__ __launch_bounds__(256)
void ucvt(const float* __restrict__ u, unsigned short* __restrict__ ub)
{
    int idx = blockIdx.x * 256 + threadIdx.x;    // MROWS*DM/8
    const float* src = u + (size_t)idx * 8;
    float4 a = *reinterpret_cast<const float4*>(src);
    float4 b = *reinterpret_cast<const float4*>(src + 4);
    unsigned short o[8];
    o[0] = f2bf(a.x); o[1] = f2bf(a.y); o[2] = f2bf(a.z); o[3] = f2bf(a.w);
    o[4] = f2bf(b.x); o[5] = f2bf(b.y); o[6] = f2bf(b.z); o[7] = f2bf(b.w);
    *reinterpret_cast<uint4*>(&ub[(size_t)idx * 8]) = *reinterpret_cast<const uint4*>(o);
}

// ---------------------------------------------------------------------------
// MFMA bf16 GEMM, m97 structure: 128x128 tile, 4 waves (2x2), BK=32,
// global_load_lds staging, 16x mfma_f32_16x16x32_bf16 per K-step.
//   C[M][N](ldc) = A_bf16[M][K](lda) * B_bf16[N][K]^T
// OMODE: 0 = write bf16 bounded by Nreal, 1 = write f32
// ---------------------------------------------------------------------------
template<int OMODE>
__global__ __launch_bounds__(256)
void gemm_mfma(const unsigned short* __restrict__ Ap, int lda,
               const unsigned short* __restrict__ Bp, int K,
               void* __restrict__ Cp, int ldc, int Nreal)
{
    __shared__ alignas(16) unsigned short As[128 * 32];
    __shared__ alignas(16) unsigned short Bs[128 * 32];

    const int t = threadIdx.x;
    const int l = t & 63;
    const int bm = blockIdx.y * 128, bn = blockIdx.x * 128;
    const int wm = ((t >> 6) >> 1) * 64, wn = ((t >> 6) & 1) * 64;

    f32x4 acc[4][4];
    #pragma unroll
    for (int i = 0; i < 4; i++)
        #pragma unroll
        for (int j = 0; j < 4; j++)
            acc[i][j] = (f32x4){0.f, 0.f, 0.f, 0.f};

    for (int k0 = 0; k0 < K; k0 += 32) {
        #pragma unroll
        for (int i = 0; i < 2; i++) {
            int c = i * 256 + t;
            int row = c >> 2, ke = (c & 3) * 8;
            gll16(Ap + (size_t)(bm + row) * lda + k0 + ke, (char*)&As[0] + c * 16);
        }
        #pragma unroll
        for (int i = 0; i < 2; i++) {
            int c = i * 256 + t;
            int row = c >> 2, ke = (c & 3) * 8;
            gll16(Bp + (size_t)(bn + row) * K + k0 + ke, (char*)&Bs[0] + c * 16);
        }
        __syncthreads();

        bf16x8 af[4], bfr[4];
        #pragma unroll
        for (int mi = 0; mi < 4; mi++)
            af[mi] = *reinterpret_cast<const bf16x8*>(
                &As[(wm + mi * 16 + (l & 15)) * 32 + (l >> 4) * 8]);
        #pragma unroll
        for (int nj = 0; nj < 4; nj++)
            bfr[nj] = *reinterpret_cast<const bf16x8*>(
                &Bs[(wn + nj * 16 + (l & 15)) * 32 + (l >> 4) * 8]);
        #pragma unroll
        for (int mi = 0; mi < 4; mi++)
            #pragma unroll
            for (int nj = 0; nj < 4; nj++)
                acc[mi][nj] = __builtin_amdgcn_mfma_f32_16x16x32_bf16(
                    af[mi], bfr[nj], acc[mi][nj], 0, 0, 0);
        __syncthreads();
    }

    const int col_l = l & 15, rgrp = (l >> 4) * 4;
    #pragma unroll
    for (int mi = 0; mi < 4; mi++) {
        #pragma unroll
        for (int r = 0; r < 4; r++) {
            int gm = bm + wm + mi * 16 + rgrp + r;
            #pragma unroll
            for (int nj = 0; nj < 4; nj++) {
                int gn = bn + wn + nj * 16 + col_l;
                float v = acc[mi][nj][r];
                if (OMODE == 0) {
                    if (gn < Nreal)
                        ((unsigned short*)Cp)[(size_t)gm * ldc + gn] = f2bf(v);
                } else {
                    ((float*)Cp)[(size_t)gm * ldc + gn] = v;
                }
            }
        }
    }
}

// ---------------------------------------------------------------------------
// Depthwise causal conv (k=4) + SiLU, bf16, 8 channels/thread (vectorized).
// dir=1 reads reversed. Output in branch coordinates.
// ---------------------------------------------------------------------------
__global__ __launch_bounds__(256)
void conv_kernel(const unsigned short* __restrict__ zx, const float* __restrict__ cw,
                 const float* __restrict__ cb, unsigned short* __restrict__ xc, int dir)
{
    int idx = blockIdx.x * 256 + threadIdx.x;   // MROWS * (CDIM/8)
    int c8 = idx % (CDIM / 8);
    int rb = idx / (CDIM / 8);
    int rr = rb & (LL - 1);
    int b  = rb >> 12;
    int c  = c8 * 8;

    float acc[8];
    {
        float4 b0 = *reinterpret_cast<const float4*>(&cb[c]);
        float4 b1 = *reinterpret_cast<const float4*>(&cb[c + 4]);
        acc[0] = b0.x; acc[1] = b0.y; acc[2] = b0.z; acc[3] = b0.w;
        acc[4] = b1.x; acc[5] = b1.y; acc[6] = b1.z; acc[7] = b1.w;
    }
    #pragma unroll
    for (int k = 0; k < 4; k++) {
        int rsrc = rr - 3 + k;
        if (rsrc < 0) continue;
        int l = dir ? (LL - 1 - rsrc) : rsrc;
        const unsigned short* src = &zx[(size_t)(b * LL + l) * DIP + DI + c];
        ushort4 v0 = *reinterpret_cast<const ushort4*>(src);
        ushort4 v1 = *reinterpret_cast<const ushort4*>(src + 4);
        unsigned short xv[8] = {v0.x, v0.y, v0.z, v0.w, v1.x, v1.y, v1.z, v1.w};
        #pragma unroll
        for (int ch = 0; ch < 8; ch++)
            acc[ch] = fmaf(cw[(c + ch) * 4 + k], bf2f(xv[ch]), acc[ch]);
    }
    unsigned short o[8];
    #pragma unroll
    for (int ch = 0; ch < 8; ch++) o[ch] = f2bf(silu_f(acc[ch]));
    *reinterpret_cast<uint4*>(&xc[(size_t)rb * CDIM + c]) = *reinterpret_cast<const uint4*>(o);
}

// ---------------------------------------------------------------------------
// Chunk states: S_c[p][n] = sum_j exp(A*(cum_{Q-1}-cum_j)) dt_j x_j[p] B_j[n]
// dt computed inline from zx. One block per (bh, chunk).
// ---------------------------------------------------------------------------
__global__ __launch_bounds__(256)
void ssd_state(const unsigned short* __restrict__ xc, const unsigned short* __restrict__ zx,
               const float* __restrict__ dtb, const float* __restrict__ A_log,
               unsigned short* __restrict__ hbuf, float* __restrict__ dtsum, int dir)
{
    int bh = blockIdx.x / NC;
    int c  = blockIdx.x % NC;
    int b = bh >> 4, h = bh & 15;
    float Ah = -expf(A_log[h]);
    float dtbh = dtb[h];
    int row0 = b * LL + c * Q;

    __shared__ unsigned short Xs[Q][132];
    __shared__ float wB[Q][68];
    __shared__ float dts_s[Q];
    __shared__ float cum_s[Q];

    const int tid = threadIdx.x;

    for (int idx = tid; idx < Q * 32; idx += 256) {
        int i = idx >> 5, p4 = (idx & 31) * 4;
        *reinterpret_cast<ushort4*>(&Xs[i][p4]) =
            *reinterpret_cast<const ushort4*>(&xc[(size_t)(row0 + i) * CDIM + h * HD + p4]);
    }
    if (tid < Q) {
        int rr = c * Q + tid;
        int l = dir ? (LL - 1 - rr) : rr;
        dts_s[tid] = softplus_f(bf2f(zx[(size_t)(b * LL + l) * DIP + (DIP - NH) + h]) + dtbh);
    }
    __syncthreads();
    if (tid < Q) {
        float s = 0.f;
        for (int k = 0; k <= tid; k++) s += dts_s[k];
        cum_s[tid] = s;
    }
    __syncthreads();
    float cumlast = cum_s[Q - 1];
    if (tid == 0) dtsum[bh * NC + c] = cumlast;
    for (int idx = tid; idx < Q * DS; idx += 256) {
        int j = idx >> 6, n = idx & 63;
        float w = expf(Ah * (cumlast - cum_s[j])) * dts_s[j];
        wB[j][n] = w * bf2f(xc[(size_t)(row0 + j) * CDIM + DI + n]);
    }
    __syncthreads();

    int tn = tid & 7, tp = tid >> 3;
    float acc[4][8] = {};
    for (int j = 0; j < Q; j++) {
        float xv[4], wv[8];
        #pragma unroll
        for (int i = 0; i < 4; i++) xv[i] = bf2f(Xs[j][tp * 4 + i]);
        #pragma unroll
        for (int k = 0; k < 8; k++) wv[k] = wB[j][tn * 8 + k];
        #pragma unroll
        for (int i = 0; i < 4; i++)
            #pragma unroll
            for (int k = 0; k < 8; k++)
                acc[i][k] = fmaf(xv[i], wv[k], acc[i][k]);
    }
    size_t hb = ((size_t)c * BH + bh) * (HD * DS);
    #pragma unroll
    for (int i = 0; i < 4; i++) {
        unsigned short tmp[8];
        #pragma unroll
        for (int k = 0; k < 8; k++) tmp[k] = f2bf(acc[i][k]);
        size_t base = hb + (size_t)(tp * 4 + i) * DS + tn * 8;
        *reinterpret_cast<ushort4*>(&hbuf[base])     = *reinterpret_cast<ushort4*>(&tmp[0]);
        *reinterpret_cast<ushort4*>(&hbuf[base + 4]) = *reinterpret_cast<ushort4*>(&tmp[4]);
    }
}

// ---------------------------------------------------------------------------
// Inter-chunk recurrence (in place: slot c gets h_init BEFORE chunk c).
// ---------------------------------------------------------------------------
__global__ __launch_bounds__(256)
void ssd_interchunk(unsigned short* __restrict__ hbuf, const float* __restrict__ dtsum,
                    const float* __restrict__ A_log)
{
    int bh  = blockIdx.x >> 5;
    int seg = blockIdx.x & 31;
    int h = bh & 15;
    float Ah = -expf(A_log[h]);
    int off = seg * 256 + threadIdx.x;
    float hst = 0.f;
    for (int c = 0; c < NC; c++) {
        size_t idx = ((size_t)c * BH + bh) * (HD * DS) + off;
        float s = bf2f(hbuf[idx]);
        hbuf[idx] = f2bf(hst);
        hst = fmaf(hst, expf(Ah * dtsum[bh * NC + c]), s);
    }
}

// ---------------------------------------------------------------------------
// Intra-chunk output + inter contribution + D*x, in place into xc x-cols.
// dt computed inline from zx.
// ---------------------------------------------------------------------------
__global__ __launch_bounds__(256)
void ssd_intra(unsigned short* __restrict__ xc, const unsigned short* __restrict__ hbuf,
               const unsigned short* __restrict__ zx, const float* __restrict__ dtb,
               const float* __restrict__ A_log, const float* __restrict__ Dv, int dir)
{
    int bh = blockIdx.x / NC;
    int c  = blockIdx.x % NC;
    int b = bh >> 4, h = bh & 15;
    float Ah = -expf(A_log[h]);
    float Dh = Dv[h];
    float dtbh = dtb[h];
    int row0 = b * LL + c * Q;

    __shared__ unsigned short Xs[Q][132];
    __shared__ unsigned short Bs[Q][70];
    __shared__ unsigned short Cs[Q][70];
    __shared__ unsigned short Ms[Q][68];
    __shared__ unsigned short hsT[DS][132];
    __shared__ float dts_s[Q];
    __shared__ float cum_s[Q];

    const int tid = threadIdx.x;

    for (int idx = tid; idx < Q * 32; idx += 256) {
        int i = idx >> 5, p4 = (idx & 31) * 4;
        *reinterpret_cast<ushort4*>(&Xs[i][p4]) =
            *reinterpret_cast<const ushort4*>(&xc[(size_t)(row0 + i) * CDIM + h * HD + p4]);
    }
    for (int idx = tid; idx < Q * 32; idx += 256) {
        int j = idx >> 5, n2 = (idx & 31) * 2;
        *reinterpret_cast<ushort2*>(&Bs[j][n2]) =
            *reinterpret_cast<const ushort2*>(&xc[(size_t)(row0 + j) * CDIM + DI + n2]);
        *reinterpret_cast<ushort2*>(&Cs[j][n2]) =
            *reinterpret_cast<const ushort2*>(&xc[(size_t)(row0 + j) * CDIM + DI + DS + n2]);
    }
    {
        size_t hb = ((size_t)c * BH + bh) * (HD * DS);
        for (int idx = tid; idx < HD * DS; idx += 256) {
            int n = idx & 63, p = idx >> 6;
            hsT[n][p] = hbuf[hb + idx];
        }
    }
    if (tid < Q) {
        int rr = c * Q + tid;
        int l = dir ? (LL - 1 - rr) : rr;
        dts_s[tid] = softplus_f(bf2f(zx[(size_t)(b * LL + l) * DIP + (DIP - NH) + h]) + dtbh);
    }
    __syncthreads();
    if (tid < Q) {
        float s = 0.f;
        for (int k = 0; k <= tid; k++) s += dts_s[k];
        cum_s[tid] = s;
    }
    __syncthreads();

    // G = C B^T -> masked, weighted -> Ms (bf16)
    {
        int ti = tid >> 4, tj = tid & 15;
        float acc[4][4] = {};
        for (int n = 0; n < DS; n++) {
            float cv[4], bv[4];
            #pragma unroll
            for (int i = 0; i < 4; i++) cv[i] = bf2f(Cs[ti * 4 + i][n]);
            #pragma unroll
            for (int j = 0; j < 4; j++) bv[j] = bf2f(Bs[tj * 4 + j][n]);
            #pragma unroll
            for (int i = 0; i < 4; i++)
                #pragma unroll
                for (int j = 0; j < 4; j++)
                    acc[i][j] = fmaf(cv[i], bv[j], acc[i][j]);
        }
        #pragma unroll
        for (int ii = 0; ii < 4; ii++) {
            int i = ti * 4 + ii;
            #pragma unroll
            for (int jj = 0; jj < 4; jj++) {
                int j = tj * 4 + jj;
                float w = (j <= i) ? expf(Ah * (cum_s[i] - cum_s[j])) * dts_s[j] : 0.f;
                Ms[i][j] = f2bf(acc[ii][jj] * w);
            }
        }
    }
    __syncthreads();

    {
        int ti = tid >> 4, tp = tid & 15;
        float acc[4][8] = {};
        float acc2[4][8] = {};
        for (int j = 0; j < Q; j++) {
            float mv[4], xv[8];
            #pragma unroll
            for (int ii = 0; ii < 4; ii++) mv[ii] = bf2f(Ms[ti * 4 + ii][j]);
            #pragma unroll
            for (int k = 0; k < 8; k++) xv[k] = bf2f(Xs[j][tp * 8 + k]);
            #pragma unroll
            for (int ii = 0; ii < 4; ii++)
                #pragma unroll
                for (int k = 0; k < 8; k++)
                    acc[ii][k] = fmaf(mv[ii], xv[k], acc[ii][k]);
        }
        for (int n = 0; n < DS; n++) {
            float cv[4], hv[8];
            #pragma unroll
            for (int ii = 0; ii < 4; ii++) cv[ii] = bf2f(Cs[ti * 4 + ii][n]);
            #pragma unroll
            for (int k = 0; k < 8; k++) hv[k] = bf2f(hsT[n][tp * 8 + k]);
            #pragma unroll
            for (int ii = 0; ii < 4; ii++)
                #pragma unroll
                for (int k = 0; k < 8; k++)
                    acc2[ii][k] = fmaf(cv[ii], hv[k], acc2[ii][k]);
        }
        #pragma unroll
        for (int ii = 0; ii < 4; ii++) {
            int i = ti * 4 + ii;
            float Pi = expf(Ah * cum_s[i]);
            unsigned short tmp[8];
            #pragma unroll
            for (int k = 0; k < 8; k++) {
                float xval = bf2f(Xs[i][tp * 8 + k]);
                tmp[k] = f2bf(fmaf(Dh, xval, fmaf(Pi, acc2[ii][k], acc[ii][k])));
            }
            size_t base = (size_t)(row0 + i) * CDIM + h * HD + tp * 8;
            *reinterpret_cast<ushort4*>(&xc[base])     = *reinterpret_cast<ushort4*>(&tmp[0]);
            *reinterpret_cast<ushort4*>(&xc[base + 4]) = *reinterpret_cast<ushort4*>(&tmp[4]);
        }
    }
}

// ---------------------------------------------------------------------------
// Gated RMSNorm. dir=0: write normed row in place (xout row == own row).
// dir=1: accumulate normed row into xout at the original (reversed) row.
// Vectorized 8 ch/thread.
// ---------------------------------------------------------------------------
__global__ __launch_bounds__(256)
void branch_final(const unsigned short* __restrict__ xcin, const unsigned short* __restrict__ zx,
                  const float* __restrict__ nw, unsigned short* __restrict__ xout, int dir)
{
    int row = blockIdx.x;
    int rr = row & (LL - 1);
    int b  = row >> 12;
    int l  = dir ? (LL - 1 - rr) : rr;

    const unsigned short* yrow = xcin + (size_t)row * CDIM;
    const unsigned short* zrow = zx + (size_t)(b * LL + l) * DIP;
    int c = threadIdx.x * 8;

    float v[8];
    float ss = 0.f;
    {
        ushort4 y0 = *reinterpret_cast<const ushort4*>(&yrow[c]);
        ushort4 y1 = *reinterpret_cast<const ushort4*>(&yrow[c + 4]);
        ushort4 z0 = *reinterpret_cast<const ushort4*>(&zrow[c]);
        ushort4 z1 = *reinterpret_cast<const ushort4*>(&zrow[c + 4]);
        unsigned short yv[8] = {y0.x, y0.y, y0.z, y0.w, y1.x, y1.y, y1.z, y1.w};
        unsigned short zv[8] = {z0.x, z0.y, z0.z, z0.w, z1.x, z1.y, z1.z, z1.w};
        #pragma unroll
        for (int ch = 0; ch < 8; ch++) {
            float val = bf2f(yv[ch]) * silu_f(bf2f(zv[ch]));
            v[ch] = val;
            ss = fmaf(val, val, ss);
        }
    }
    #pragma unroll
    for (int o = 32; o > 0; o >>= 1) ss += __shfl_down(ss, o);
    __shared__ float red[4];
    if ((threadIdx.x & 63) == 0) red[threadIdx.x >> 6] = ss;
    __syncthreads();
    ss = red[0] + red[1] + red[2] + red[3];
    float scale = rsqrtf(ss * (1.f / DI) + 1e-5f);

    float w[8];
    {
        float4 w0 = *reinterpret_cast<const float4*>(&nw[c]);
        float4 w1 = *reinterpret_cast<const float4*>(&nw[c + 4]);
        w[0] = w0.x; w[1] = w0.y; w[2] = w0.z; w[3] = w0.w;
        w[4] = w1.x; w[5] = w1.y; w[6] = w1.z; w[7] = w1.w;
    }

    unsigned short* orow = xout + (size_t)(b * LL + l) * CDIM;
    unsigned short o[8];
    if (dir) {
        ushort4 p0 = *reinterpret_cast<const ushort4*>(&orow[c]);
        ushort4 p1 = *reinterpret_cast<const ushort4*>(&orow[c + 4]);
        unsigned short pv[8] = {p0.x, p0.y, p0.z, p0.w, p1.x, p1.y, p1.z, p1.w};
        #pragma unroll
        for (int ch = 0; ch < 8; ch++)
            o[ch] = f2bf(bf2f(pv[ch]) + v[ch] * scale * w[ch]);
    } else {
        #pragma unroll
        for (int ch = 0; ch < 8; ch++)
            o[ch] = f2bf(v[ch] * scale * w[ch]);
    }
    *reinterpret_cast<uint4*>(&orow[c]) = *reinterpret_cast<const uint4*>(o);
}

// ---------------------------------------------------------------------------
extern "C" void kernel_launch(void* const* d_in, const int* in_sizes, int n_in,
                              void* d_out, int out_size, void* d_ws, size_t ws_size,
                              hipStream_t stream)
{
    const float* u       = (const float*)d_in[0];
    const float* w_in    = (const float*)d_in[1];
    const float* conv_w  = (const float*)d_in[2];
    const float* conv_b  = (const float*)d_in[3];
    const float* conv_wb = (const float*)d_in[4];
    const float* conv_bb = (const float*)d_in[5];
    const float* dt_bias  = (const float*)d_in[6];
    const float* dt_biasb = (const float*)d_in[7];
    const float* A_log   = (const float*)d_in[8];
    const float* A_b_log = (const float*)d_in[9];
    const float* Dp      = (const float*)d_in[10];
    const float* D_b     = (const float*)d_in[11];
    const float* norm_w  = (const float*)d_in[12];
    const float* w_out   = (const float*)d_in[13];
    float* out = (float*)d_out;

    unsigned short* zx    = (unsigned short*)d_ws;               // MROWS*DIP
    unsigned short* xc    = zx + (size_t)MROWS * DIP;            // MROWS*CDIM
    unsigned short* xc2   = xc + (size_t)MROWS * CDIM;           // MROWS*CDIM
    unsigned short* hb_ub = xc2 + (size_t)MROWS * CDIM;          // max(hbuf, ub) = NC*BH*HD*DS
    unsigned short* wbin  = hb_ub + (size_t)NC * BH * HD * DS;   // DIPP*DM
    unsigned short* wbout = wbin + (size_t)DIPP * DM;            // DM*DI
    float* dtsum = (float*)(wbout + (size_t)DM * DI);            // BH*NC
    // total ~187.5 MB

    unsigned short* ub   = hb_ub;   // live: step 0-1 only
    unsigned short* hbuf = hb_ub;   // live: step 2 onward

    // 0. weight + activation conversion to bf16
    cvt_pad<<<(DIPP * (DM / 4) + 255) / 256, 256, 0, stream>>>(w_in, wbin, DIP, DIPP, DM);
    cvt_pad<<<(DM * (DI / 4) + 255) / 256, 256, 0, stream>>>(w_out, wbout, DM, DM, DI);
    ucvt<<<(MROWS * DM / 8) / 256, 256, 0, stream>>>(u, ub);

    // 1. zxbcdt = u @ in_proj_w^T  (bf16 out, MFMA)
    {
        dim3 grid(DIPP / 128, MROWS / 128);
        gemm_mfma<0><<<grid, 256, 0, stream>>>(ub, DM, wbin, DM, zx, DIP, DIP);
    }

    // 2. per-direction branch; dir1's final accumulates into xc (orig coords)
    for (int dir = 0; dir < 2; dir++) {
        const float* cw  = dir ? conv_wb  : conv_w;
        const float* cb  = dir ? conv_bb  : conv_b;
        const float* dtb = dir ? dt_biasb : dt_bias;
        const float* Al  = dir ? A_b_log  : A_log;
        const float* Dd  = dir ? D_b      : Dp;
        unsigned short* xb = dir ? xc2 : xc;

        conv_kernel<<<(MROWS * (CDIM / 8)) / 256, 256, 0, stream>>>(zx, cw, cb, xb, dir);
        ssd_state<<<BH * NC, 256, 0, stream>>>(xb, zx, dtb, Al, hbuf, dtsum, dir);
        ssd_interchunk<<<BH * 32, 256, 0, stream>>>(hbuf, dtsum, Al);
        ssd_intra<<<BH * NC, 256, 0, stream>>>(xb, hbuf, zx, dtb, Al, Dd, dir);
        branch_final<<<MROWS, 256, 0, stream>>>(xb, zx, norm_w, xc, dir);
    }

    // 3. out = (y_fw + rev(y_bw)) @ out_proj_w^T  (single MFMA GEMM)
    {
        dim3 grid(DM / 128, MROWS / 128);
        gemm_mfma<1><<<grid, 256, 0, stream>>>(xc, CDIM, wbout, DI, out, DM, DM);
    }
}

// Round 6
// 711.584 us; speedup vs baseline: 8.9685x; 1.2622x over previous
//
#include <hip/hip_runtime.h>
#include <hip/hip_bf16.h>
#include <math.h>

#define BB 2
#define LL 4096
#define DM 1024
#define DIP 4240
#define DIPP 4352          // padded N for in-proj (34*128)
#define DI 2048
#define NH 16
#define HD 128
#define DS 64
#define CDIM 2176
#define MROWS (BB*LL)
#define Q 64
#define NC (LL/Q)
#define BH (BB*NH)
#define STR 72             // LDS row stride (ushorts): 144B = 36 dwords -> 2-way banks

typedef __attribute__((ext_vector_type(8))) short bf16x8;
typedef __attribute__((ext_vector_type(4))) float f32x4;

__device__ __forceinline__ float silu_f(float x) { return x / (1.f + expf(-x)); }
__device__ __forceinline__ float softplus_f(float x) {
    return fmaxf(x, 0.f) + log1pf(expf(-fabsf(x)));
}
__device__ __forceinline__ float bf2f(unsigned short u) {
    return __uint_as_float(((unsigned int)u) << 16);
}
__device__ __forceinline__ unsigned short f2bf(float f) {
    unsigned int x = __float_as_uint(f);
    return (unsigned short)((x + 0x7fff + ((x >> 16) & 1)) >> 16);
}
__device__ __forceinline__ void gll16(const void* g, void* l) {
    __builtin_amdgcn_global_load_lds(
        (const __attribute__((address_space(1))) void*)g,
        (__attribute__((address_space(3))) void*)l,
        16, 0, 0);
}

// ---------------------------------------------------------------------------
// fp32 -> bf16 weight conversion with optional row padding (pad rows = 0)
// ---------------------------------------------------------------------------
__global__ __launch_bounds__(256)
void cvt_pad(const float* __restrict__ in, unsigned short* __restrict__ out,
             int rows_real, int rows_pad, int cols)
{
    int idx = blockIdx.x * 256 + threadIdx.x;
    int cols4 = cols >> 2;
    int total = rows_pad * cols4;
    if (idx >= total) return;
    int row = idx / cols4;
    int c4 = (idx - row * cols4) * 4;
    ushort4 o;
    if (row < rows_real) {
        float4 v = *reinterpret_cast<const float4*>(&in[(size_t)row * cols + c4]);
        o.x = f2bf(v.x); o.y = f2bf(v.y); o.z = f2bf(v.z); o.w = f2bf(v.w);
    } else {
        o = make_ushort4(0, 0, 0, 0);
    }
    *reinterpret_cast<ushort4*>(&out[(size_t)row * cols + c4]) = o;
}

// ---------------------------------------------------------------------------
// u fp32 -> bf16 (contiguous, 8 elems/thread)
// ---------------------------------------------------------------------------
__global__ __launch_bounds__(256)
void ucvt(const float* __restrict__ u, unsigned short* __restrict__ ub)
{
    int idx = blockIdx.x * 256 + threadIdx.x;    // MROWS*DM/8
    const float* src = u + (size_t)idx * 8;
    float4 a = *reinterpret_cast<const float4*>(src);
    float4 b = *reinterpret_cast<const float4*>(src + 4);
    unsigned short o[8];
    o[0] = f2bf(a.x); o[1] = f2bf(a.y); o[2] = f2bf(a.z); o[3] = f2bf(a.w);
    o[4] = f2bf(b.x); o[5] = f2bf(b.y); o[6] = f2bf(b.z); o[7] = f2bf(b.w);
    *reinterpret_cast<uint4*>(&ub[(size_t)idx * 8]) = *reinterpret_cast<const uint4*>(o);
}

// ---------------------------------------------------------------------------
// MFMA bf16 GEMM, m97 structure: 128x128 tile, 4 waves (2x2), BK=32.
//   C[M][N](ldc) = A_bf16[M][K](lda) * B_bf16[N][K]^T
// OMODE: 0 = write bf16 bounded by Nreal, 1 = write f32
// ---------------------------------------------------------------------------
template<int OMODE>
__global__ __launch_bounds__(256)
void gemm_mfma(const unsigned short* __restrict__ Ap, int lda,
               const unsigned short* __restrict__ Bp, int K,
               void* __restrict__ Cp, int ldc, int Nreal)
{
    __shared__ alignas(16) unsigned short As[128 * 32];
    __shared__ alignas(16) unsigned short Bs[128 * 32];

    const int t = threadIdx.x;
    const int l = t & 63;
    const int bm = blockIdx.y * 128, bn = blockIdx.x * 128;
    const int wm = ((t >> 6) >> 1) * 64, wn = ((t >> 6) & 1) * 64;

    f32x4 acc[4][4];
    #pragma unroll
    for (int i = 0; i < 4; i++)
        #pragma unroll
        for (int j = 0; j < 4; j++)
            acc[i][j] = (f32x4){0.f, 0.f, 0.f, 0.f};

    for (int k0 = 0; k0 < K; k0 += 32) {
        #pragma unroll
        for (int i = 0; i < 2; i++) {
            int c = i * 256 + t;
            int row = c >> 2, ke = (c & 3) * 8;
            gll16(Ap + (size_t)(bm + row) * lda + k0 + ke, (char*)&As[0] + c * 16);
        }
        #pragma unroll
        for (int i = 0; i < 2; i++) {
            int c = i * 256 + t;
            int row = c >> 2, ke = (c & 3) * 8;
            gll16(Bp + (size_t)(bn + row) * K + k0 + ke, (char*)&Bs[0] + c * 16);
        }
        __syncthreads();

        bf16x8 af[4], bfr[4];
        #pragma unroll
        for (int mi = 0; mi < 4; mi++)
            af[mi] = *reinterpret_cast<const bf16x8*>(
                &As[(wm + mi * 16 + (l & 15)) * 32 + (l >> 4) * 8]);
        #pragma unroll
        for (int nj = 0; nj < 4; nj++)
            bfr[nj] = *reinterpret_cast<const bf16x8*>(
                &Bs[(wn + nj * 16 + (l & 15)) * 32 + (l >> 4) * 8]);
        #pragma unroll
        for (int mi = 0; mi < 4; mi++)
            #pragma unroll
            for (int nj = 0; nj < 4; nj++)
                acc[mi][nj] = __builtin_amdgcn_mfma_f32_16x16x32_bf16(
                    af[mi], bfr[nj], acc[mi][nj], 0, 0, 0);
        __syncthreads();
    }

    const int col_l = l & 15, rgrp = (l >> 4) * 4;
    #pragma unroll
    for (int mi = 0; mi < 4; mi++) {
        #pragma unroll
        for (int r = 0; r < 4; r++) {
            int gm = bm + wm + mi * 16 + rgrp + r;
            #pragma unroll
            for (int nj = 0; nj < 4; nj++) {
                int gn = bn + wn + nj * 16 + col_l;
                float v = acc[mi][nj][r];
                if (OMODE == 0) {
                    if (gn < Nreal)
                        ((unsigned short*)Cp)[(size_t)gm * ldc + gn] = f2bf(v);
                } else {
                    ((float*)Cp)[(size_t)gm * ldc + gn] = v;
                }
            }
        }
    }
}

// ---------------------------------------------------------------------------
// Depthwise causal conv (k=4) + SiLU, bf16, 8 channels/thread (vectorized).
// ---------------------------------------------------------------------------
__global__ __launch_bounds__(256)
void conv_kernel(const unsigned short* __restrict__ zx, const float* __restrict__ cw,
                 const float* __restrict__ cb, unsigned short* __restrict__ xc, int dir)
{
    int idx = blockIdx.x * 256 + threadIdx.x;   // MROWS * (CDIM/8)
    int c8 = idx % (CDIM / 8);
    int rb = idx / (CDIM / 8);
    int rr = rb & (LL - 1);
    int b  = rb >> 12;
    int c  = c8 * 8;

    float acc[8];
    {
        float4 b0 = *reinterpret_cast<const float4*>(&cb[c]);
        float4 b1 = *reinterpret_cast<const float4*>(&cb[c + 4]);
        acc[0] = b0.x; acc[1] = b0.y; acc[2] = b0.z; acc[3] = b0.w;
        acc[4] = b1.x; acc[5] = b1.y; acc[6] = b1.z; acc[7] = b1.w;
    }
    #pragma unroll
    for (int k = 0; k < 4; k++) {
        int rsrc = rr - 3 + k;
        if (rsrc < 0) continue;
        int l = dir ? (LL - 1 - rsrc) : rsrc;
        const unsigned short* src = &zx[(size_t)(b * LL + l) * DIP + DI + c];
        ushort4 v0 = *reinterpret_cast<const ushort4*>(src);
        ushort4 v1 = *reinterpret_cast<const ushort4*>(src + 4);
        unsigned short xv[8] = {v0.x, v0.y, v0.z, v0.w, v1.x, v1.y, v1.z, v1.w};
        #pragma unroll
        for (int ch = 0; ch < 8; ch++)
            acc[ch] = fmaf(cw[(c + ch) * 4 + k], bf2f(xv[ch]), acc[ch]);
    }
    unsigned short o[8];
    #pragma unroll
    for (int ch = 0; ch < 8; ch++) o[ch] = f2bf(silu_f(acc[ch]));
    *reinterpret_cast<uint4*>(&xc[(size_t)rb * CDIM + c]) = *reinterpret_cast<const uint4*>(o);
}

// ---------------------------------------------------------------------------
// Chunk states via MFMA: S[p][n] = sum_j X[j][p] * w_j * B_j[n]
// XT staged transposed+XOR-swizzled; wBT staged transposed.
// ---------------------------------------------------------------------------
__global__ __launch_bounds__(256)
void ssd_state(const unsigned short* __restrict__ xc, const unsigned short* __restrict__ zx,
               const float* __restrict__ dtb, const float* __restrict__ A_log,
               unsigned short* __restrict__ hbuf, float* __restrict__ dtsum, int dir)
{
    int bh = blockIdx.x / NC;
    int c  = blockIdx.x % NC;
    int b = bh >> 4, h = bh & 15;
    float Ah = -expf(A_log[h]);
    float dtbh = dtb[h];
    int row0 = b * LL + c * Q;

    __shared__ alignas(16) unsigned short XT[128 * STR];
    __shared__ alignas(16) unsigned short wBT[64 * STR];
    __shared__ float dts_s[Q];
    __shared__ float cum_s[Q];

    const int tid = threadIdx.x;
    const int l = tid & 63;
    const int wid = tid >> 6;

    // stage X transposed: XT[p][ j ^ mask(p) ], mask(p)=((p>>3)&7)<<3
    #pragma unroll
    for (int it = 0; it < 4; it++) {
        int idx = it * 256 + tid;
        int j = idx >> 4;
        int pblk = idx & 15;
        const unsigned short* src = &xc[(size_t)(row0 + j) * CDIM + h * HD + pblk * 8];
        ushort4 v0 = *reinterpret_cast<const ushort4*>(src);
        ushort4 v1 = *reinterpret_cast<const ushort4*>(src + 4);
        unsigned short xv[8] = {v0.x, v0.y, v0.z, v0.w, v1.x, v1.y, v1.z, v1.w};
        int jx = j ^ ((pblk & 7) << 3);
        #pragma unroll
        for (int e = 0; e < 8; e++)
            XT[(pblk * 8 + e) * STR + jx] = xv[e];
    }
    if (tid < Q) {
        int rr = c * Q + tid;
        int ls = dir ? (LL - 1 - rr) : rr;
        dts_s[tid] = softplus_f(bf2f(zx[(size_t)(b * LL + ls) * DIP + (DIP - NH) + h]) + dtbh);
    }
    __syncthreads();
    if (tid < Q) {
        float s = 0.f;
        for (int k = 0; k <= tid; k++) s += dts_s[k];
        cum_s[tid] = s;
    }
    __syncthreads();
    float cumlast = cum_s[Q - 1];
    if (tid == 0) dtsum[bh * NC + c] = cumlast;

    // wBT[n][j] = exp(Ah*(cumlast-cum_j))*dt_j * B_j[n]
    #pragma unroll
    for (int it = 0; it < 2; it++) {
        int idx = it * 256 + tid;
        int j = idx >> 3, n0 = (idx & 7) * 8;
        const unsigned short* src = &xc[(size_t)(row0 + j) * CDIM + DI + n0];
        ushort4 v0 = *reinterpret_cast<const ushort4*>(src);
        ushort4 v1 = *reinterpret_cast<const ushort4*>(src + 4);
        unsigned short bv[8] = {v0.x, v0.y, v0.z, v0.w, v1.x, v1.y, v1.z, v1.w};
        float wj = expf(Ah * (cumlast - cum_s[j])) * dts_s[j];
        #pragma unroll
        for (int e = 0; e < 8; e++)
            wBT[(n0 + e) * STR + j] = f2bf(wj * bf2f(bv[e]));
    }
    __syncthreads();

    // S[p][n] = sum_j XT[p][j] wBT[n][j]; wave wid owns rows wid*32..+32
    f32x4 acc[2][4];
    #pragma unroll
    for (int i = 0; i < 2; i++)
        #pragma unroll
        for (int j = 0; j < 4; j++)
            acc[i][j] = (f32x4){0.f, 0.f, 0.f, 0.f};

    const int p0w = wid * 32;
    #pragma unroll
    for (int kk = 0; kk < 2; kk++) {
        bf16x8 af[2], bfr[4];
        #pragma unroll
        for (int mi = 0; mi < 2; mi++) {
            int p = p0w + mi * 16 + (l & 15);
            int col = (kk * 32 + (l >> 4) * 8) ^ (((p >> 3) & 7) << 3);
            af[mi] = *reinterpret_cast<const bf16x8*>(&XT[p * STR + col]);
        }
        #pragma unroll
        for (int nj = 0; nj < 4; nj++)
            bfr[nj] = *reinterpret_cast<const bf16x8*>(
                &wBT[(nj * 16 + (l & 15)) * STR + kk * 32 + (l >> 4) * 8]);
        #pragma unroll
        for (int mi = 0; mi < 2; mi++)
            #pragma unroll
            for (int nj = 0; nj < 4; nj++)
                acc[mi][nj] = __builtin_amdgcn_mfma_f32_16x16x32_bf16(
                    af[mi], bfr[nj], acc[mi][nj], 0, 0, 0);
    }

    size_t hb = ((size_t)c * BH + bh) * (HD * DS);
    #pragma unroll
    for (int mi = 0; mi < 2; mi++)
        #pragma unroll
        for (int r = 0; r < 4; r++) {
            int p = p0w + mi * 16 + (l >> 4) * 4 + r;
            #pragma unroll
            for (int nj = 0; nj < 4; nj++) {
                int n = nj * 16 + (l & 15);
                hbuf[hb + (size_t)p * DS + n] = f2bf(acc[mi][nj][r]);
            }
        }
}

// ---------------------------------------------------------------------------
// Inter-chunk recurrence (in place: slot c gets h_init BEFORE chunk c).
// ---------------------------------------------------------------------------
__global__ __launch_bounds__(256)
void ssd_interchunk(unsigned short* __restrict__ hbuf, const float* __restrict__ dtsum,
                    const float* __restrict__ A_log)
{
    int bh  = blockIdx.x >> 5;
    int seg = blockIdx.x & 31;
    int h = bh & 15;
    float Ah = -expf(A_log[h]);
    int off = seg * 256 + threadIdx.x;
    float hst = 0.f;
    for (int c = 0; c < NC; c++) {
        size_t idx = ((size_t)c * BH + bh) * (HD * DS) + off;
        float s = bf2f(hbuf[idx]);
        hbuf[idx] = f2bf(hst);
        hst = fmaf(hst, expf(Ah * dtsum[bh * NC + c]), s);
    }
}

// ---------------------------------------------------------------------------
// Intra-chunk output via MFMA. Y = M·X + Pi*(C·h_init) with D folded into
// the diagonal of M. Output bounced through LDS for coalesced writes.
// ---------------------------------------------------------------------------
__global__ __launch_bounds__(256)
void ssd_intra(unsigned short* __restrict__ xc, const unsigned short* __restrict__ hbuf,
               const unsigned short* __restrict__ zx, const float* __restrict__ dtb,
               const float* __restrict__ A_log, const float* __restrict__ Dv, int dir)
{
    int bh = blockIdx.x / NC;
    int c  = blockIdx.x % NC;
    int b = bh >> 4, h = bh & 15;
    float Ah = -expf(A_log[h]);
    float Dh = Dv[h];
    float dtbh = dtb[h];
    int row0 = b * LL + c * Q;

    __shared__ alignas(16) unsigned short Cm[64 * STR];
    __shared__ alignas(16) unsigned short Bm[64 * STR];
    __shared__ alignas(16) unsigned short Mw[64 * STR];
    __shared__ alignas(16) unsigned short XT[128 * STR];
    __shared__ alignas(16) unsigned short hm[128 * STR];
    __shared__ float dts_s[Q];
    __shared__ float cum_s[Q];

    const int tid = threadIdx.x;
    const int l = tid & 63;
    const int wid = tid >> 6;

    // ---- stage XT (transposed + swizzled) ----
    #pragma unroll
    for (int it = 0; it < 4; it++) {
        int idx = it * 256 + tid;
        int j = idx >> 4;
        int pblk = idx & 15;
        const unsigned short* src = &xc[(size_t)(row0 + j) * CDIM + h * HD + pblk * 8];
        ushort4 v0 = *reinterpret_cast<const ushort4*>(src);
        ushort4 v1 = *reinterpret_cast<const ushort4*>(src + 4);
        unsigned short xv[8] = {v0.x, v0.y, v0.z, v0.w, v1.x, v1.y, v1.z, v1.w};
        int jx = j ^ ((pblk & 7) << 3);
        #pragma unroll
        for (int e = 0; e < 8; e++)
            XT[(pblk * 8 + e) * STR + jx] = xv[e];
    }
    // ---- stage B, C (row-major, K=n) ----
    #pragma unroll
    for (int it = 0; it < 2; it++) {
        int idx = it * 256 + tid;
        int j = idx >> 3, n0 = (idx & 7) * 8;
        *reinterpret_cast<uint4*>(&Bm[j * STR + n0]) =
            *reinterpret_cast<const uint4*>(&xc[(size_t)(row0 + j) * CDIM + DI + n0]);
        *reinterpret_cast<uint4*>(&Cm[j * STR + n0]) =
            *reinterpret_cast<const uint4*>(&xc[(size_t)(row0 + j) * CDIM + DI + DS + n0]);
    }
    // ---- stage h_init [p][n] ----
    {
        size_t hb = ((size_t)c * BH + bh) * (HD * DS);
        #pragma unroll
        for (int it = 0; it < 4; it++) {
            int idx = it * 256 + tid;
            int p = idx >> 3, n0 = (idx & 7) * 8;
            *reinterpret_cast<uint4*>(&hm[p * STR + n0]) =
                *reinterpret_cast<const uint4*>(&hbuf[hb + (size_t)p * DS + n0]);
        }
    }
    if (tid < Q) {
        int rr = c * Q + tid;
        int ls = dir ? (LL - 1 - rr) : rr;
        dts_s[tid] = softplus_f(bf2f(zx[(size_t)(b * LL + ls) * DIP + (DIP - NH) + h]) + dtbh);
    }
    __syncthreads();
    if (tid < Q) {
        float s = 0.f;
        for (int k = 0; k <= tid; k++) s += dts_s[k];
        cum_s[tid] = s;
    }
    __syncthreads();

    // ---- phase 1: G = C·B^T -> masked/weighted + D on diagonal -> Mw ----
    {
        const int i0 = (wid >> 1) * 32, j0 = (wid & 1) * 32;
        f32x4 g[2][2];
        #pragma unroll
        for (int i = 0; i < 2; i++)
            #pragma unroll
            for (int j = 0; j < 2; j++)
                g[i][j] = (f32x4){0.f, 0.f, 0.f, 0.f};
        #pragma unroll
        for (int kk = 0; kk < 2; kk++) {
            bf16x8 ca[2], bb[2];
            #pragma unroll
            for (int mi = 0; mi < 2; mi++)
                ca[mi] = *reinterpret_cast<const bf16x8*>(
                    &Cm[(i0 + mi * 16 + (l & 15)) * STR + kk * 32 + (l >> 4) * 8]);
            #pragma unroll
            for (int nj = 0; nj < 2; nj++)
                bb[nj] = *reinterpret_cast<const bf16x8*>(
                    &Bm[(j0 + nj * 16 + (l & 15)) * STR + kk * 32 + (l >> 4) * 8]);
            #pragma unroll
            for (int mi = 0; mi < 2; mi++)
                #pragma unroll
                for (int nj = 0; nj < 2; nj++)
                    g[mi][nj] = __builtin_amdgcn_mfma_f32_16x16x32_bf16(
                        ca[mi], bb[nj], g[mi][nj], 0, 0, 0);
        }
        #pragma unroll
        for (int mi = 0; mi < 2; mi++)
            #pragma unroll
            for (int nj = 0; nj < 2; nj++)
                #pragma unroll
                for (int r = 0; r < 4; r++) {
                    int i = i0 + mi * 16 + (l >> 4) * 4 + r;
                    int j = j0 + nj * 16 + (l & 15);
                    float wgt = 0.f;
                    if (j < i)       wgt = expf(Ah * (cum_s[i] - cum_s[j])) * dts_s[j];
                    else if (j == i) wgt = dts_s[j];
                    float mv = g[mi][nj][r] * wgt + (j == i ? Dh : 0.f);
                    Mw[i * STR + j] = f2bf(mv);
                }
    }
    __syncthreads();

    // ---- phase 2: Y = Mw·X (via XT) + Pi * Cm·hm ----
    const int yi0 = (wid >> 1) * 32, yp0 = (wid & 1) * 64;
    f32x4 y1[2][4], y2[2][4];
    #pragma unroll
    for (int i = 0; i < 2; i++)
        #pragma unroll
        for (int j = 0; j < 4; j++) {
            y1[i][j] = (f32x4){0.f, 0.f, 0.f, 0.f};
            y2[i][j] = (f32x4){0.f, 0.f, 0.f, 0.f};
        }
    #pragma unroll
    for (int kk = 0; kk < 2; kk++) {
        bf16x8 ma[2], xb[4];
        #pragma unroll
        for (int mi = 0; mi < 2; mi++)
            ma[mi] = *reinterpret_cast<const bf16x8*>(
                &Mw[(yi0 + mi * 16 + (l & 15)) * STR + kk * 32 + (l >> 4) * 8]);
        #pragma unroll
        for (int nj = 0; nj < 4; nj++) {
            int p = yp0 + nj * 16 + (l & 15);
            int col = (kk * 32 + (l >> 4) * 8) ^ (((p >> 3) & 7) << 3);
            xb[nj] = *reinterpret_cast<const bf16x8*>(&XT[p * STR + col]);
        }
        #pragma unroll
        for (int mi = 0; mi < 2; mi++)
            #pragma unroll
            for (int nj = 0; nj < 4; nj++)
                y1[mi][nj] = __builtin_amdgcn_mfma_f32_16x16x32_bf16(
                    ma[mi], xb[nj], y1[mi][nj], 0, 0, 0);
    }
    #pragma unroll
    for (int kk = 0; kk < 2; kk++) {
        bf16x8 ca[2], hbf[4];
        #pragma unroll
        for (int mi = 0; mi < 2; mi++)
            ca[mi] = *reinterpret_cast<const bf16x8*>(
                &Cm[(yi0 + mi * 16 + (l & 15)) * STR + kk * 32 + (l >> 4) * 8]);
        #pragma unroll
        for (int nj = 0; nj < 4; nj++)
            hbf[nj] = *reinterpret_cast<const bf16x8*>(
                &hm[(yp0 + nj * 16 + (l & 15)) * STR + kk * 32 + (l >> 4) * 8]);
        #pragma unroll
        for (int mi = 0; mi < 2; mi++)
            #pragma unroll
            for (int nj = 0; nj < 4; nj++)
                y2[mi][nj] = __builtin_amdgcn_mfma_f32_16x16x32_bf16(
                    ca[mi], hbf[nj], y2[mi][nj], 0, 0, 0);
    }
    __syncthreads();   // all XT reads done before aliasing it with Y

    // ---- epilogue: Y -> LDS (alias XT) -> coalesced global write ----
    unsigned short* Yl = &XT[0];   // [64][136]
    #pragma unroll
    for (int mi = 0; mi < 2; mi++)
        #pragma unroll
        for (int r = 0; r < 4; r++) {
            int i = yi0 + mi * 16 + (l >> 4) * 4 + r;
            float Pi = expf(Ah * cum_s[i]);
            #pragma unroll
            for (int nj = 0; nj < 4; nj++) {
                int p = yp0 + nj * 16 + (l & 15);
                Yl[i * 136 + p] = f2bf(y1[mi][nj][r] + Pi * y2[mi][nj][r]);
            }
        }
    __syncthreads();
    #pragma unroll
    for (int it = 0; it < 4; it++) {
        int idx = it * 256 + tid;
        int i = idx >> 4, p0 = (idx & 15) * 8;
        *reinterpret_cast<uint4*>(&xc[(size_t)(row0 + i) * CDIM + h * HD + p0]) =
            *reinterpret_cast<const uint4*>(&Yl[i * 136 + p0]);
    }
}

// ---------------------------------------------------------------------------
// Gated RMSNorm. dir=0: write normed row in place; dir=1: accumulate into
// xout at original (reversed) row. Vectorized 8 ch/thread.
// ---------------------------------------------------------------------------
__global__ __launch_bounds__(256)
void branch_final(const unsigned short* __restrict__ xcin, const unsigned short* __restrict__ zx,
                  const float* __restrict__ nw, unsigned short* __restrict__ xout, int dir)
{
    int row = blockIdx.x;
    int rr = row & (LL - 1);
    int b  = row >> 12;
    int l  = dir ? (LL - 1 - rr) : rr;

    const unsigned short* yrow = xcin + (size_t)row * CDIM;
    const unsigned short* zrow = zx + (size_t)(b * LL + l) * DIP;
    int c = threadIdx.x * 8;

    float v[8];
    float ss = 0.f;
    {
        ushort4 y0 = *reinterpret_cast<const ushort4*>(&yrow[c]);
        ushort4 y1 = *reinterpret_cast<const ushort4*>(&yrow[c + 4]);
        ushort4 z0 = *reinterpret_cast<const ushort4*>(&zrow[c]);
        ushort4 z1 = *reinterpret_cast<const ushort4*>(&zrow[c + 4]);
        unsigned short yv[8] = {y0.x, y0.y, y0.z, y0.w, y1.x, y1.y, y1.z, y1.w};
        unsigned short zv[8] = {z0.x, z0.y, z0.z, z0.w, z1.x, z1.y, z1.z, z1.w};
        #pragma unroll
        for (int ch = 0; ch < 8; ch++) {
            float val = bf2f(yv[ch]) * silu_f(bf2f(zv[ch]));
            v[ch] = val;
            ss = fmaf(val, val, ss);
        }
    }
    #pragma unroll
    for (int o = 32; o > 0; o >>= 1) ss += __shfl_down(ss, o);
    __shared__ float red[4];
    if ((threadIdx.x & 63) == 0) red[threadIdx.x >> 6] = ss;
    __syncthreads();
    ss = red[0] + red[1] + red[2] + red[3];
    float scale = rsqrtf(ss * (1.f / DI) + 1e-5f);

    float w[8];
    {
        float4 w0 = *reinterpret_cast<const float4*>(&nw[c]);
        float4 w1 = *reinterpret_cast<const float4*>(&nw[c + 4]);
        w[0] = w0.x; w[1] = w0.y; w[2] = w0.z; w[3] = w0.w;
        w[4] = w1.x; w[5] = w1.y; w[6] = w1.z; w[7] = w1.w;
    }

    unsigned short* orow = xout + (size_t)(b * LL + l) * CDIM;
    unsigned short o[8];
    if (dir) {
        ushort4 p0 = *reinterpret_cast<const ushort4*>(&orow[c]);
        ushort4 p1 = *reinterpret_cast<const ushort4*>(&orow[c + 4]);
        unsigned short pv[8] = {p0.x, p0.y, p0.z, p0.w, p1.x, p1.y, p1.z, p1.w};
        #pragma unroll
        for (int ch = 0; ch < 8; ch++)
            o[ch] = f2bf(bf2f(pv[ch]) + v[ch] * scale * w[ch]);
    } else {
        #pragma unroll
        for (int ch = 0; ch < 8; ch++)
            o[ch] = f2bf(v[ch] * scale * w[ch]);
    }
    *reinterpret_cast<uint4*>(&orow[c]) = *reinterpret_cast<const uint4*>(o);
}

// ---------------------------------------------------------------------------
extern "C" void kernel_launch(void* const* d_in, const int* in_sizes, int n_in,
                              void* d_out, int out_size, void* d_ws, size_t ws_size,
                              hipStream_t stream)
{
    const float* u       = (const float*)d_in[0];
    const float* w_in    = (const float*)d_in[1];
    const float* conv_w  = (const float*)d_in[2];
    const float* conv_b  = (const float*)d_in[3];
    const float* conv_wb = (const float*)d_in[4];
    const float* conv_bb = (const float*)d_in[5];
    const float* dt_bias  = (const float*)d_in[6];
    const float* dt_biasb = (const float*)d_in[7];
    const float* A_log   = (const float*)d_in[8];
    const float* A_b_log = (const float*)d_in[9];
    const float* Dp      = (const float*)d_in[10];
    const float* D_b     = (const float*)d_in[11];
    const float* norm_w  = (const float*)d_in[12];
    const float* w_out   = (const float*)d_in[13];
    float* out = (float*)d_out;

    unsigned short* zx    = (unsigned short*)d_ws;               // MROWS*DIP
    unsigned short* xc    = zx + (size_t)MROWS * DIP;            // MROWS*CDIM
    unsigned short* xc2   = xc + (size_t)MROWS * CDIM;           // MROWS*CDIM
    unsigned short* hb_ub = xc2 + (size_t)MROWS * CDIM;          // max(hbuf, ub)
    unsigned short* wbin  = hb_ub + (size_t)NC * BH * HD * DS;   // DIPP*DM
    unsigned short* wbout = wbin + (size_t)DIPP * DM;            // DM*DI
    float* dtsum = (float*)(wbout + (size_t)DM * DI);            // BH*NC

    unsigned short* ub   = hb_ub;   // live: step 0-1 only
    unsigned short* hbuf = hb_ub;   // live: step 2 onward

    // 0. weight + activation conversion to bf16
    cvt_pad<<<(DIPP * (DM / 4) + 255) / 256, 256, 0, stream>>>(w_in, wbin, DIP, DIPP, DM);
    cvt_pad<<<(DM * (DI / 4) + 255) / 256, 256, 0, stream>>>(w_out, wbout, DM, DM, DI);
    ucvt<<<(MROWS * DM / 8) / 256, 256, 0, stream>>>(u, ub);

    // 1. zxbcdt = u @ in_proj_w^T  (bf16 out, MFMA)
    {
        dim3 grid(DIPP / 128, MROWS / 128);
        gemm_mfma<0><<<grid, 256, 0, stream>>>(ub, DM, wbin, DM, zx, DIP, DIP);
    }

    // 2. per-direction branch; dir1's final accumulates into xc (orig coords)
    for (int dir = 0; dir < 2; dir++) {
        const float* cw  = dir ? conv_wb  : conv_w;
        const float* cb  = dir ? conv_bb  : conv_b;
        const float* dtb = dir ? dt_biasb : dt_bias;
        const float* Al  = dir ? A_b_log  : A_log;
        const float* Dd  = dir ? D_b      : Dp;
        unsigned short* xb = dir ? xc2 : xc;

        conv_kernel<<<(MROWS * (CDIM / 8)) / 256, 256, 0, stream>>>(zx, cw, cb, xb, dir);
        ssd_state<<<BH * NC, 256, 0, stream>>>(xb, zx, dtb, Al, hbuf, dtsum, dir);
        ssd_interchunk<<<BH * 32, 256, 0, stream>>>(hbuf, dtsum, Al);
        ssd_intra<<<BH * NC, 256, 0, stream>>>(xb, hbuf, zx, dtb, Al, Dd, dir);
        branch_final<<<MROWS, 256, 0, stream>>>(xb, zx, norm_w, xc, dir);
    }

    // 3. out = (y_fw + rev(y_bw)) @ out_proj_w^T  (single MFMA GEMM)
    {
        dim3 grid(DM / 128, MROWS / 128);
        gemm_mfma<1><<<grid, 256, 0, stream>>>(xc, CDIM, wbout, DI, out, DM, DM);
    }
}

// Round 7
// 513.258 us; speedup vs baseline: 12.4340x; 1.3864x over previous
//
#include <hip/hip_runtime.h>
#include <hip/hip_bf16.h>
#include <math.h>

#define BB 2
#define LL 4096
#define DM 1024
#define DIP 4240
#define DIPP 4352          // padded N for in-proj (34*128)
#define DI 2048
#define NH 16
#define HD 128
#define DS 64
#define CDIM 2176
#define MROWS (BB*LL)
#define Q 64
#define NC (LL/Q)
#define BH (BB*NH)
#define STR 72             // LDS row stride (ushorts): 144B = 36 dwords -> 2-way banks
#define CCH 16             // conv rows per thread
#define NCHK (LL/CCH)      // conv chunks per batch

typedef __attribute__((ext_vector_type(8))) short bf16x8;
typedef __attribute__((ext_vector_type(4))) float f32x4;

__device__ __forceinline__ float silu_f(float x) { return x / (1.f + expf(-x)); }
__device__ __forceinline__ float softplus_f(float x) {
    return fmaxf(x, 0.f) + log1pf(expf(-fabsf(x)));
}
__device__ __forceinline__ float bf2f(unsigned short u) {
    return __uint_as_float(((unsigned int)u) << 16);
}
__device__ __forceinline__ unsigned short f2bf(float f) {
    unsigned int x = __float_as_uint(f);
    return (unsigned short)((x + 0x7fff + ((x >> 16) & 1)) >> 16);
}
__device__ __forceinline__ void gll16(const void* g, void* l) {
    __builtin_amdgcn_global_load_lds(
        (const __attribute__((address_space(1))) void*)g,
        (__attribute__((address_space(3))) void*)l,
        16, 0, 0);
}

// ---------------------------------------------------------------------------
// fp32 -> bf16 weight conversion with optional row padding (pad rows = 0)
// ---------------------------------------------------------------------------
__global__ __launch_bounds__(256)
void cvt_pad(const float* __restrict__ in, unsigned short* __restrict__ out,
             int rows_real, int rows_pad, int cols)
{
    int idx = blockIdx.x * 256 + threadIdx.x;
    int cols4 = cols >> 2;
    int total = rows_pad * cols4;
    if (idx >= total) return;
    int row = idx / cols4;
    int c4 = (idx - row * cols4) * 4;
    ushort4 o;
    if (row < rows_real) {
        float4 v = *reinterpret_cast<const float4*>(&in[(size_t)row * cols + c4]);
        o.x = f2bf(v.x); o.y = f2bf(v.y); o.z = f2bf(v.z); o.w = f2bf(v.w);
    } else {
        o = make_ushort4(0, 0, 0, 0);
    }
    *reinterpret_cast<ushort4*>(&out[(size_t)row * cols + c4]) = o;
}

// ---------------------------------------------------------------------------
// u fp32 -> bf16 (contiguous, 8 elems/thread)
// ---------------------------------------------------------------------------
__global__ __launch_bounds__(256)
void ucvt(const float* __restrict__ u, unsigned short* __restrict__ ub)
{
    int idx = blockIdx.x * 256 + threadIdx.x;    // MROWS*DM/8
    const float* src = u + (size_t)idx * 8;
    float4 a = *reinterpret_cast<const float4*>(src);
    float4 b = *reinterpret_cast<const float4*>(src + 4);
    unsigned short o[8];
    o[0] = f2bf(a.x); o[1] = f2bf(a.y); o[2] = f2bf(a.z); o[3] = f2bf(a.w);
    o[4] = f2bf(b.x); o[5] = f2bf(b.y); o[6] = f2bf(b.z); o[7] = f2bf(b.w);
    *reinterpret_cast<uint4*>(&ub[(size_t)idx * 8]) = *reinterpret_cast<const uint4*>(o);
}

// ---------------------------------------------------------------------------
// MFMA bf16 GEMM, m97 structure: 128x128 tile, 4 waves (2x2), BK=32.
//   C[M][N](ldc) = A_bf16[M][K](lda) * B_bf16[N][K]^T
// OMODE: 0 = write bf16 bounded by Nreal, 1 = write f32
// ---------------------------------------------------------------------------
template<int OMODE>
__global__ __launch_bounds__(256)
void gemm_mfma(const unsigned short* __restrict__ Ap, int lda,
               const unsigned short* __restrict__ Bp, int K,
               void* __restrict__ Cp, int ldc, int Nreal)
{
    __shared__ alignas(16) unsigned short As[128 * 32];
    __shared__ alignas(16) unsigned short Bs[128 * 32];

    const int t = threadIdx.x;
    const int l = t & 63;
    const int bm = blockIdx.y * 128, bn = blockIdx.x * 128;
    const int wm = ((t >> 6) >> 1) * 64, wn = ((t >> 6) & 1) * 64;

    f32x4 acc[4][4];
    #pragma unroll
    for (int i = 0; i < 4; i++)
        #pragma unroll
        for (int j = 0; j < 4; j++)
            acc[i][j] = (f32x4){0.f, 0.f, 0.f, 0.f};

    for (int k0 = 0; k0 < K; k0 += 32) {
        #pragma unroll
        for (int i = 0; i < 2; i++) {
            int c = i * 256 + t;
            int row = c >> 2, ke = (c & 3) * 8;
            gll16(Ap + (size_t)(bm + row) * lda + k0 + ke, (char*)&As[0] + c * 16);
        }
        #pragma unroll
        for (int i = 0; i < 2; i++) {
            int c = i * 256 + t;
            int row = c >> 2, ke = (c & 3) * 8;
            gll16(Bp + (size_t)(bn + row) * K + k0 + ke, (char*)&Bs[0] + c * 16);
        }
        __syncthreads();

        bf16x8 af[4], bfr[4];
        #pragma unroll
        for (int mi = 0; mi < 4; mi++)
            af[mi] = *reinterpret_cast<const bf16x8*>(
                &As[(wm + mi * 16 + (l & 15)) * 32 + (l >> 4) * 8]);
        #pragma unroll
        for (int nj = 0; nj < 4; nj++)
            bfr[nj] = *reinterpret_cast<const bf16x8*>(
                &Bs[(wn + nj * 16 + (l & 15)) * 32 + (l >> 4) * 8]);
        #pragma unroll
        for (int mi = 0; mi < 4; mi++)
            #pragma unroll
            for (int nj = 0; nj < 4; nj++)
                acc[mi][nj] = __builtin_amdgcn_mfma_f32_16x16x32_bf16(
                    af[mi], bfr[nj], acc[mi][nj], 0, 0, 0);
        __syncthreads();
    }

    const int col_l = l & 15, rgrp = (l >> 4) * 4;
    #pragma unroll
    for (int mi = 0; mi < 4; mi++) {
        #pragma unroll
        for (int r = 0; r < 4; r++) {
            int gm = bm + wm + mi * 16 + rgrp + r;
            #pragma unroll
            for (int nj = 0; nj < 4; nj++) {
                int gn = bn + wn + nj * 16 + col_l;
                float v = acc[mi][nj][r];
                if (OMODE == 0) {
                    if (gn < Nreal)
                        ((unsigned short*)Cp)[(size_t)gm * ldc + gn] = f2bf(v);
                } else {
                    ((float*)Cp)[(size_t)gm * ldc + gn] = v;
                }
            }
        }
    }
}

// ---------------------------------------------------------------------------
// Fused bidirectional depthwise causal conv (k=4) + SiLU, sliding window.
// Each thread: 8 channels, CCH source rows. After loading row s, window
// {s-3..s} yields dir0 out at branch row s and dir1 out at branch row
// LL+2-s (x_rev[t+k-3] = src[(LL+2-t)-k]). Zero regs give the padding.
// ---------------------------------------------------------------------------
__global__ __launch_bounds__(256)
void conv_fused(const unsigned short* __restrict__ zx,
                const float* __restrict__ cw0, const float* __restrict__ cb0,
                const float* __restrict__ cw1, const float* __restrict__ cb1,
                unsigned short* __restrict__ x0, unsigned short* __restrict__ x1)
{
    int idx = blockIdx.x * 256 + threadIdx.x;      // 272 * BB * NCHK total
    int c8 = idx % (CDIM / 8);
    int cg = idx / (CDIM / 8);
    int b  = cg >> 8;             // NCHK = 256
    int ci = cg & (NCHK - 1);
    int c  = c8 * 8;
    int s0 = ci * CCH;

    // weights (all static-indexed)
    float wt0[4][8], wt1[4][8], bv0[8], bv1[8];
    #pragma unroll
    for (int ch = 0; ch < 8; ch++) {
        float4 q0 = *reinterpret_cast<const float4*>(&cw0[(c + ch) * 4]);
        float4 q1 = *reinterpret_cast<const float4*>(&cw1[(c + ch) * 4]);
        wt0[0][ch] = q0.x; wt0[1][ch] = q0.y; wt0[2][ch] = q0.z; wt0[3][ch] = q0.w;
        wt1[0][ch] = q1.x; wt1[1][ch] = q1.y; wt1[2][ch] = q1.z; wt1[3][ch] = q1.w;
    }
    {
        float4 a0 = *reinterpret_cast<const float4*>(&cb0[c]);
        float4 a1 = *reinterpret_cast<const float4*>(&cb0[c + 4]);
        bv0[0]=a0.x; bv0[1]=a0.y; bv0[2]=a0.z; bv0[3]=a0.w;
        bv0[4]=a1.x; bv0[5]=a1.y; bv0[6]=a1.z; bv0[7]=a1.w;
        float4 d0 = *reinterpret_cast<const float4*>(&cb1[c]);
        float4 d1 = *reinterpret_cast<const float4*>(&cb1[c + 4]);
        bv1[0]=d0.x; bv1[1]=d0.y; bv1[2]=d0.z; bv1[3]=d0.w;
        bv1[4]=d1.x; bv1[5]=d1.y; bv1[6]=d1.z; bv1[7]=d1.w;
    }

    float win[4][8];

    #define LDROW(SL, S) do {                                                  \
        if ((S) >= 0) {                                                        \
            const unsigned short* _src = &zx[((size_t)b * LL + (S)) * DIP + DI + c]; \
            ushort4 _v0 = *reinterpret_cast<const ushort4*>(_src);             \
            ushort4 _v1 = *reinterpret_cast<const ushort4*>(_src + 4);         \
            win[SL][0] = bf2f(_v0.x); win[SL][1] = bf2f(_v0.y);                \
            win[SL][2] = bf2f(_v0.z); win[SL][3] = bf2f(_v0.w);                \
            win[SL][4] = bf2f(_v1.x); win[SL][5] = bf2f(_v1.y);                \
            win[SL][6] = bf2f(_v1.z); win[SL][7] = bf2f(_v1.w);                \
        } else {                                                               \
            _Pragma("unroll")                                                  \
            for (int _e = 0; _e < 8; _e++) win[SL][_e] = 0.f;                  \
        }                                                                      \
    } while (0)

    #define ZROW(SL) do {                                                      \
        _Pragma("unroll")                                                      \
        for (int _e = 0; _e < 8; _e++) win[SL][_e] = 0.f;                      \
    } while (0)

    // out0 at branch row S: sum_k wt0[k]*win[(PH+1+k)&3]
    #define EMIT0(PH, S) do {                                                  \
        float _a[8]; unsigned short _o[8];                                     \
        _Pragma("unroll")                                                      \
        for (int _ch = 0; _ch < 8; _ch++) {                                    \
            _a[_ch] = bv0[_ch];                                                \
            _a[_ch] = fmaf(wt0[0][_ch], win[((PH)+1)&3][_ch], _a[_ch]);        \
            _a[_ch] = fmaf(wt0[1][_ch], win[((PH)+2)&3][_ch], _a[_ch]);        \
            _a[_ch] = fmaf(wt0[2][_ch], win[((PH)+3)&3][_ch], _a[_ch]);        \
            _a[_ch] = fmaf(wt0[3][_ch], win[(PH)&3][_ch], _a[_ch]);            \
            _o[_ch] = f2bf(silu_f(_a[_ch]));                                   \
        }                                                                      \
        *reinterpret_cast<uint4*>(&x0[((size_t)b * LL + (S)) * CDIM + c]) =    \
            *reinterpret_cast<const uint4*>(_o);                               \
    } while (0)

    // out1 at branch row LL+2-S: sum_k wt1[k]*win[(PH-k)&3]  (valid S>=3)
    #define EMIT1(PH, S) do {                                                  \
        float _a[8]; unsigned short _o[8];                                     \
        _Pragma("unroll")                                                      \
        for (int _ch = 0; _ch < 8; _ch++) {                                    \
            _a[_ch] = bv1[_ch];                                                \
            _a[_ch] = fmaf(wt1[0][_ch], win[(PH)&3][_ch], _a[_ch]);            \
            _a[_ch] = fmaf(wt1[1][_ch], win[((PH)+3)&3][_ch], _a[_ch]);        \
            _a[_ch] = fmaf(wt1[2][_ch], win[((PH)+2)&3][_ch], _a[_ch]);        \
            _a[_ch] = fmaf(wt1[3][_ch], win[((PH)+1)&3][_ch], _a[_ch]);        \
            _o[_ch] = f2bf(silu_f(_a[_ch]));                                   \
        }                                                                      \
        *reinterpret_cast<uint4*>(&x1[((size_t)b * LL + (LL + 2 - (S))) * CDIM + c]) = \
            *reinterpret_cast<const uint4*>(_o);                               \
    } while (0)

    // preload rows s0-3..s0-1 into slots 1,2,3 (s0 % 4 == 0)
    LDROW(1, s0 - 3);
    LDROW(2, s0 - 2);
    LDROW(3, s0 - 1);

    for (int it = 0; it < CCH; it += 4) {
        int sb = s0 + it;
        #pragma unroll
        for (int ph = 0; ph < 4; ph++) {
            int s = sb + ph;
            switch (ph) {
            case 0: LDROW(0, s); EMIT0(0, s); if (s >= 3) EMIT1(0, s); break;
            case 1: LDROW(1, s); EMIT0(1, s); if (s >= 3) EMIT1(1, s); break;
            case 2: LDROW(2, s); EMIT0(2, s); if (s >= 3) EMIT1(2, s); break;
            default: LDROW(3, s); EMIT0(3, s); if (s >= 3) EMIT1(3, s); break;
            }
        }
    }
    // tail: last chunk emits dir1 rows rb1 = 2,1,0 using zero rows s=LL..LL+2
    if (ci == NCHK - 1) {
        ZROW(0); EMIT1(0, LL);
        ZROW(1); EMIT1(1, LL + 1);
        ZROW(2); EMIT1(2, LL + 2);
    }
    #undef LDROW
    #undef ZROW
    #undef EMIT0
    #undef EMIT1
}

// ---------------------------------------------------------------------------
// Chunk states via MFMA: S[p][n] = sum_j X[j][p] * w_j * B_j[n]
// XT staged transposed+XOR-swizzled; wBT staged transposed.
// ---------------------------------------------------------------------------
__global__ __launch_bounds__(256)
void ssd_state(const unsigned short* __restrict__ xc, const unsigned short* __restrict__ zx,
               const float* __restrict__ dtb, const float* __restrict__ A_log,
               unsigned short* __restrict__ hbuf, float* __restrict__ dtsum, int dir)
{
    int bh = blockIdx.x / NC;
    int c  = blockIdx.x % NC;
    int b = bh >> 4, h = bh & 15;
    float Ah = -expf(A_log[h]);
    float dtbh = dtb[h];
    int row0 = b * LL + c * Q;

    __shared__ alignas(16) unsigned short XT[128 * STR];
    __shared__ alignas(16) unsigned short wBT[64 * STR];
    __shared__ float dts_s[Q];
    __shared__ float cum_s[Q];

    const int tid = threadIdx.x;
    const int l = tid & 63;
    const int wid = tid >> 6;

    // stage X transposed: XT[p][ j ^ mask(p) ], mask(p)=((p>>3)&7)<<3
    #pragma unroll
    for (int it = 0; it < 4; it++) {
        int idx = it * 256 + tid;
        int j = idx >> 4;
        int pblk = idx & 15;
        const unsigned short* src = &xc[(size_t)(row0 + j) * CDIM + h * HD + pblk * 8];
        ushort4 v0 = *reinterpret_cast<const ushort4*>(src);
        ushort4 v1 = *reinterpret_cast<const ushort4*>(src + 4);
        unsigned short xv[8] = {v0.x, v0.y, v0.z, v0.w, v1.x, v1.y, v1.z, v1.w};
        int jx = j ^ ((pblk & 7) << 3);
        #pragma unroll
        for (int e = 0; e < 8; e++)
            XT[(pblk * 8 + e) * STR + jx] = xv[e];
    }
    if (tid < Q) {
        int rr = c * Q + tid;
        int ls = dir ? (LL - 1 - rr) : rr;
        dts_s[tid] = softplus_f(bf2f(zx[(size_t)(b * LL + ls) * DIP + (DIP - NH) + h]) + dtbh);
    }
    __syncthreads();
    if (tid < Q) {
        float s = 0.f;
        for (int k = 0; k <= tid; k++) s += dts_s[k];
        cum_s[tid] = s;
    }
    __syncthreads();
    float cumlast = cum_s[Q - 1];
    if (tid == 0) dtsum[bh * NC + c] = cumlast;

    // wBT[n][j] = exp(Ah*(cumlast-cum_j))*dt_j * B_j[n]
    #pragma unroll
    for (int it = 0; it < 2; it++) {
        int idx = it * 256 + tid;
        int j = idx >> 3, n0 = (idx & 7) * 8;
        const unsigned short* src = &xc[(size_t)(row0 + j) * CDIM + DI + n0];
        ushort4 v0 = *reinterpret_cast<const ushort4*>(src);
        ushort4 v1 = *reinterpret_cast<const ushort4*>(src + 4);
        unsigned short bv[8] = {v0.x, v0.y, v0.z, v0.w, v1.x, v1.y, v1.z, v1.w};
        float wj = expf(Ah * (cumlast - cum_s[j])) * dts_s[j];
        #pragma unroll
        for (int e = 0; e < 8; e++)
            wBT[(n0 + e) * STR + j] = f2bf(wj * bf2f(bv[e]));
    }
    __syncthreads();

    // S[p][n] = sum_j XT[p][j] wBT[n][j]; wave wid owns rows wid*32..+32
    f32x4 acc[2][4];
    #pragma unroll
    for (int i = 0; i < 2; i++)
        #pragma unroll
        for (int j = 0; j < 4; j++)
            acc[i][j] = (f32x4){0.f, 0.f, 0.f, 0.f};

    const int p0w = wid * 32;
    #pragma unroll
    for (int kk = 0; kk < 2; kk++) {
        bf16x8 af[2], bfr[4];
        #pragma unroll
        for (int mi = 0; mi < 2; mi++) {
            int p = p0w + mi * 16 + (l & 15);
            int col = (kk * 32 + (l >> 4) * 8) ^ (((p >> 3) & 7) << 3);
            af[mi] = *reinterpret_cast<const bf16x8*>(&XT[p * STR + col]);
        }
        #pragma unroll
        for (int nj = 0; nj < 4; nj++)
            bfr[nj] = *reinterpret_cast<const bf16x8*>(
                &wBT[(nj * 16 + (l & 15)) * STR + kk * 32 + (l >> 4) * 8]);
        #pragma unroll
        for (int mi = 0; mi < 2; mi++)
            #pragma unroll
            for (int nj = 0; nj < 4; nj++)
                acc[mi][nj] = __builtin_amdgcn_mfma_f32_16x16x32_bf16(
                    af[mi], bfr[nj], acc[mi][nj], 0, 0, 0);
    }

    size_t hb = ((size_t)c * BH + bh) * (HD * DS);
    #pragma unroll
    for (int mi = 0; mi < 2; mi++)
        #pragma unroll
        for (int r = 0; r < 4; r++) {
            int p = p0w + mi * 16 + (l >> 4) * 4 + r;
            #pragma unroll
            for (int nj = 0; nj < 4; nj++) {
                int n = nj * 16 + (l & 15);
                hbuf[hb + (size_t)p * DS + n] = f2bf(acc[mi][nj][r]);
            }
        }
}

// ---------------------------------------------------------------------------
// Inter-chunk recurrence (in place: slot c gets h_init BEFORE chunk c).
// ---------------------------------------------------------------------------
__global__ __launch_bounds__(256)
void ssd_interchunk(unsigned short* __restrict__ hbuf, const float* __restrict__ dtsum,
                    const float* __restrict__ A_log)
{
    int bh  = blockIdx.x >> 5;
    int seg = blockIdx.x & 31;
    int h = bh & 15;
    float Ah = -expf(A_log[h]);
    int off = seg * 256 + threadIdx.x;
    float hst = 0.f;
    for (int c = 0; c < NC; c++) {
        size_t idx = ((size_t)c * BH + bh) * (HD * DS) + off;
        float s = bf2f(hbuf[idx]);
        hbuf[idx] = f2bf(hst);
        hst = fmaf(hst, expf(Ah * dtsum[bh * NC + c]), s);
    }
}

// ---------------------------------------------------------------------------
// Intra-chunk output via MFMA. Y = M·X + Pi*(C·h_init) with D folded into
// the diagonal of M. Output bounced through LDS for coalesced writes.
// ---------------------------------------------------------------------------
__global__ __launch_bounds__(256)
void ssd_intra(unsigned short* __restrict__ xc, const unsigned short* __restrict__ hbuf,
               const unsigned short* __restrict__ zx, const float* __restrict__ dtb,
               const float* __restrict__ A_log, const float* __restrict__ Dv, int dir)
{
    int bh = blockIdx.x / NC;
    int c  = blockIdx.x % NC;
    int b = bh >> 4, h = bh & 15;
    float Ah = -expf(A_log[h]);
    float Dh = Dv[h];
    float dtbh = dtb[h];
    int row0 = b * LL + c * Q;

    __shared__ alignas(16) unsigned short Cm[64 * STR];
    __shared__ alignas(16) unsigned short Bm[64 * STR];
    __shared__ alignas(16) unsigned short Mw[64 * STR];
    __shared__ alignas(16) unsigned short XT[128 * STR];
    __shared__ alignas(16) unsigned short hm[128 * STR];
    __shared__ float dts_s[Q];
    __shared__ float cum_s[Q];

    const int tid = threadIdx.x;
    const int l = tid & 63;
    const int wid = tid >> 6;

    // ---- stage XT (transposed + swizzled) ----
    #pragma unroll
    for (int it = 0; it < 4; it++) {
        int idx = it * 256 + tid;
        int j = idx >> 4;
        int pblk = idx & 15;
        const unsigned short* src = &xc[(size_t)(row0 + j) * CDIM + h * HD + pblk * 8];
        ushort4 v0 = *reinterpret_cast<const ushort4*>(src);
        ushort4 v1 = *reinterpret_cast<const ushort4*>(src + 4);
        unsigned short xv[8] = {v0.x, v0.y, v0.z, v0.w, v1.x, v1.y, v1.z, v1.w};
        int jx = j ^ ((pblk & 7) << 3);
        #pragma unroll
        for (int e = 0; e < 8; e++)
            XT[(pblk * 8 + e) * STR + jx] = xv[e];
    }
    // ---- stage B, C (row-major, K=n) ----
    #pragma unroll
    for (int it = 0; it < 2; it++) {
        int idx = it * 256 + tid;
        int j = idx >> 3, n0 = (idx & 7) * 8;
        *reinterpret_cast<uint4*>(&Bm[j * STR + n0]) =
            *reinterpret_cast<const uint4*>(&xc[(size_t)(row0 + j) * CDIM + DI + n0]);
        *reinterpret_cast<uint4*>(&Cm[j * STR + n0]) =
            *reinterpret_cast<const uint4*>(&xc[(size_t)(row0 + j) * CDIM + DI + DS + n0]);
    }
    // ---- stage h_init [p][n] ----
    {
        size_t hb = ((size_t)c * BH + bh) * (HD * DS);
        #pragma unroll
        for (int it = 0; it < 4; it++) {
            int idx = it * 256 + tid;
            int p = idx >> 3, n0 = (idx & 7) * 8;
            *reinterpret_cast<uint4*>(&hm[p * STR + n0]) =
                *reinterpret_cast<const uint4*>(&hbuf[hb + (size_t)p * DS + n0]);
        }
    }
    if (tid < Q) {
        int rr = c * Q + tid;
        int ls = dir ? (LL - 1 - rr) : rr;
        dts_s[tid] = softplus_f(bf2f(zx[(size_t)(b * LL + ls) * DIP + (DIP - NH) + h]) + dtbh);
    }
    __syncthreads();
    if (tid < Q) {
        float s = 0.f;
        for (int k = 0; k <= tid; k++) s += dts_s[k];
        cum_s[tid] = s;
    }
    __syncthreads();

    // ---- phase 1: G = C·B^T -> masked/weighted + D on diagonal -> Mw ----
    {
        const int i0 = (wid >> 1) * 32, j0 = (wid & 1) * 32;
        f32x4 g[2][2];
        #pragma unroll
        for (int i = 0; i < 2; i++)
            #pragma unroll
            for (int j = 0; j < 2; j++)
                g[i][j] = (f32x4){0.f, 0.f, 0.f, 0.f};
        #pragma unroll
        for (int kk = 0; kk < 2; kk++) {
            bf16x8 ca[2], bb[2];
            #pragma unroll
            for (int mi = 0; mi < 2; mi++)
                ca[mi] = *reinterpret_cast<const bf16x8*>(
                    &Cm[(i0 + mi * 16 + (l & 15)) * STR + kk * 32 + (l >> 4) * 8]);
            #pragma unroll
            for (int nj = 0; nj < 2; nj++)
                bb[nj] = *reinterpret_cast<const bf16x8*>(
                    &Bm[(j0 + nj * 16 + (l & 15)) * STR + kk * 32 + (l >> 4) * 8]);
            #pragma unroll
            for (int mi = 0; mi < 2; mi++)
                #pragma unroll
                for (int nj = 0; nj < 2; nj++)
                    g[mi][nj] = __builtin_amdgcn_mfma_f32_16x16x32_bf16(
                        ca[mi], bb[nj], g[mi][nj], 0, 0, 0);
        }
        #pragma unroll
        for (int mi = 0; mi < 2; mi++)
            #pragma unroll
            for (int nj = 0; nj < 2; nj++)
                #pragma unroll
                for (int r = 0; r < 4; r++) {
                    int i = i0 + mi * 16 + (l >> 4) * 4 + r;
                    int j = j0 + nj * 16 + (l & 15);
                    float wgt = 0.f;
                    if (j < i)       wgt = expf(Ah * (cum_s[i] - cum_s[j])) * dts_s[j];
                    else if (j == i) wgt = dts_s[j];
                    float mv = g[mi][nj][r] * wgt + (j == i ? Dh : 0.f);
                    Mw[i * STR + j] = f2bf(mv);
                }
    }
    __syncthreads();

    // ---- phase 2: Y = Mw·X (via XT) + Pi * Cm·hm ----
    const int yi0 = (wid >> 1) * 32, yp0 = (wid & 1) * 64;
    f32x4 y1[2][4], y2[2][4];
    #pragma unroll
    for (int i = 0; i < 2; i++)
        #pragma unroll
        for (int j = 0; j < 4; j++) {
            y1[i][j] = (f32x4){0.f, 0.f, 0.f, 0.f};
            y2[i][j] = (f32x4){0.f, 0.f, 0.f, 0.f};
        }
    #pragma unroll
    for (int kk = 0; kk < 2; kk++) {
        bf16x8 ma[2], xb[4];
        #pragma unroll
        for (int mi = 0; mi < 2; mi++)
            ma[mi] = *reinterpret_cast<const bf16x8*>(
                &Mw[(yi0 + mi * 16 + (l & 15)) * STR + kk * 32 + (l >> 4) * 8]);
        #pragma unroll
        for (int nj = 0; nj < 4; nj++) {
            int p = yp0 + nj * 16 + (l & 15);
            int col = (kk * 32 + (l >> 4) * 8) ^ (((p >> 3) & 7) << 3);
            xb[nj] = *reinterpret_cast<const bf16x8*>(&XT[p * STR + col]);
        }
        #pragma unroll
        for (int mi = 0; mi < 2; mi++)
            #pragma unroll
            for (int nj = 0; nj < 4; nj++)
                y1[mi][nj] = __builtin_amdgcn_mfma_f32_16x16x32_bf16(
                    ma[mi], xb[nj], y1[mi][nj], 0, 0, 0);
    }
    #pragma unroll
    for (int kk = 0; kk < 2; kk++) {
        bf16x8 ca[2], hbf[4];
        #pragma unroll
        for (int mi = 0; mi < 2; mi++)
            ca[mi] = *reinterpret_cast<const bf16x8*>(
                &Cm[(yi0 + mi * 16 + (l & 15)) * STR + kk * 32 + (l >> 4) * 8]);
        #pragma unroll
        for (int nj = 0; nj < 4; nj++)
            hbf[nj] = *reinterpret_cast<const bf16x8*>(
                &hm[(yp0 + nj * 16 + (l & 15)) * STR + kk * 32 + (l >> 4) * 8]);
        #pragma unroll
        for (int mi = 0; mi < 2; mi++)
            #pragma unroll
            for (int nj = 0; nj < 4; nj++)
                y2[mi][nj] = __builtin_amdgcn_mfma_f32_16x16x32_bf16(
                    ca[mi], hbf[nj], y2[mi][nj], 0, 0, 0);
    }
    __syncthreads();   // all XT reads done before aliasing it with Y

    // ---- epilogue: Y -> LDS (alias XT) -> coalesced global write ----
    unsigned short* Yl = &XT[0];   // [64][136]
    #pragma unroll
    for (int mi = 0; mi < 2; mi++)
        #pragma unroll
        for (int r = 0; r < 4; r++) {
            int i = yi0 + mi * 16 + (l >> 4) * 4 + r;
            float Pi = expf(Ah * cum_s[i]);
            #pragma unroll
            for (int nj = 0; nj < 4; nj++) {
                int p = yp0 + nj * 16 + (l & 15);
                Yl[i * 136 + p] = f2bf(y1[mi][nj][r] + Pi * y2[mi][nj][r]);
            }
        }
    __syncthreads();
    #pragma unroll
    for (int it = 0; it < 4; it++) {
        int idx = it * 256 + tid;
        int i = idx >> 4, p0 = (idx & 15) * 8;
        *reinterpret_cast<uint4*>(&xc[(size_t)(row0 + i) * CDIM + h * HD + p0]) =
            *reinterpret_cast<const uint4*>(&Yl[i * 136 + p0]);
    }
}

// ---------------------------------------------------------------------------
// Gated RMSNorm. dir=0: write normed row in place; dir=1: accumulate into
// xout at original (reversed) row. Vectorized 8 ch/thread.
// ---------------------------------------------------------------------------
__global__ __launch_bounds__(256)
void branch_final(const unsigned short* __restrict__ xcin, const unsigned short* __restrict__ zx,
                  const float* __restrict__ nw, unsigned short* __restrict__ xout, int dir)
{
    int row = blockIdx.x;
    int rr = row & (LL - 1);
    int b  = row >> 12;
    int l  = dir ? (LL - 1 - rr) : rr;

    const unsigned short* yrow = xcin + (size_t)row * CDIM;
    const unsigned short* zrow = zx + (size_t)(b * LL + l) * DIP;
    int c = threadIdx.x * 8;

    float v[8];
    float ss = 0.f;
    {
        ushort4 y0 = *reinterpret_cast<const ushort4*>(&yrow[c]);
        ushort4 y1 = *reinterpret_cast<const ushort4*>(&yrow[c + 4]);
        ushort4 z0 = *reinterpret_cast<const ushort4*>(&zrow[c]);
        ushort4 z1 = *reinterpret_cast<const ushort4*>(&zrow[c + 4]);
        unsigned short yv[8] = {y0.x, y0.y, y0.z, y0.w, y1.x, y1.y, y1.z, y1.w};
        unsigned short zv[8] = {z0.x, z0.y, z0.z, z0.w, z1.x, z1.y, z1.z, z1.w};
        #pragma unroll
        for (int ch = 0; ch < 8; ch++) {
            float val = bf2f(yv[ch]) * silu_f(bf2f(zv[ch]));
            v[ch] = val;
            ss = fmaf(val, val, ss);
        }
    }
    #pragma unroll
    for (int o = 32; o > 0; o >>= 1) ss += __shfl_down(ss, o);
    __shared__ float red[4];
    if ((threadIdx.x & 63) == 0) red[threadIdx.x >> 6] = ss;
    __syncthreads();
    ss = red[0] + red[1] + red[2] + red[3];
    float scale = rsqrtf(ss * (1.f / DI) + 1e-5f);

    float w[8];
    {
        float4 w0 = *reinterpret_cast<const float4*>(&nw[c]);
        float4 w1 = *reinterpret_cast<const float4*>(&nw[c + 4]);
        w[0] = w0.x; w[1] = w0.y; w[2] = w0.z; w[3] = w0.w;
        w[4] = w1.x; w[5] = w1.y; w[6] = w1.z; w[7] = w1.w;
    }

    unsigned short* orow = xout + (size_t)(b * LL + l) * CDIM;
    unsigned short o[8];
    if (dir) {
        ushort4 p0 = *reinterpret_cast<const ushort4*>(&orow[c]);
        ushort4 p1 = *reinterpret_cast<const ushort4*>(&orow[c + 4]);
        unsigned short pv[8] = {p0.x, p0.y, p0.z, p0.w, p1.x, p1.y, p1.z, p1.w};
        #pragma unroll
        for (int ch = 0; ch < 8; ch++)
            o[ch] = f2bf(bf2f(pv[ch]) + v[ch] * scale * w[ch]);
    } else {
        #pragma unroll
        for (int ch = 0; ch < 8; ch++)
            o[ch] = f2bf(v[ch] * scale * w[ch]);
    }
    *reinterpret_cast<uint4*>(&orow[c]) = *reinterpret_cast<const uint4*>(o);
}

// ---------------------------------------------------------------------------
extern "C" void kernel_launch(void* const* d_in, const int* in_sizes, int n_in,
                              void* d_out, int out_size, void* d_ws, size_t ws_size,
                              hipStream_t stream)
{
    const float* u       = (const float*)d_in[0];
    const float* w_in    = (const float*)d_in[1];
    const float* conv_w  = (const float*)d_in[2];
    const float* conv_b  = (const float*)d_in[3];
    const float* conv_wb = (const float*)d_in[4];
    const float* conv_bb = (const float*)d_in[5];
    const float* dt_bias  = (const float*)d_in[6];
    const float* dt_biasb = (const float*)d_in[7];
    const float* A_log   = (const float*)d_in[8];
    const float* A_b_log = (const float*)d_in[9];
    const float* Dp      = (const float*)d_in[10];
    const float* D_b     = (const float*)d_in[11];
    const float* norm_w  = (const float*)d_in[12];
    const float* w_out   = (const float*)d_in[13];
    float* out = (float*)d_out;

    unsigned short* zx    = (unsigned short*)d_ws;               // MROWS*DIP
    unsigned short* xc    = zx + (size_t)MROWS * DIP;            // MROWS*CDIM
    unsigned short* xc2   = xc + (size_t)MROWS * CDIM;           // MROWS*CDIM
    unsigned short* hb_ub = xc2 + (size_t)MROWS * CDIM;          // max(hbuf, ub)
    unsigned short* wbin  = hb_ub + (size_t)NC * BH * HD * DS;   // DIPP*DM
    unsigned short* wbout = wbin + (size_t)DIPP * DM;            // DM*DI
    float* dtsum = (float*)(wbout + (size_t)DM * DI);            // BH*NC

    unsigned short* ub   = hb_ub;   // live: step 0-1 only
    unsigned short* hbuf = hb_ub;   // live: step 2 onward

    // 0. weight + activation conversion to bf16
    cvt_pad<<<(DIPP * (DM / 4) + 255) / 256, 256, 0, stream>>>(w_in, wbin, DIP, DIPP, DM);
    cvt_pad<<<(DM * (DI / 4) + 255) / 256, 256, 0, stream>>>(w_out, wbout, DM, DM, DI);
    ucvt<<<(MROWS * DM / 8) / 256, 256, 0, stream>>>(u, ub);

    // 1. zxbcdt = u @ in_proj_w^T  (bf16 out, MFMA)
    {
        dim3 grid(DIPP / 128, MROWS / 128);
        gemm_mfma<0><<<grid, 256, 0, stream>>>(ub, DM, wbin, DM, zx, DIP, DIP);
    }

    // 1b. fused bidirectional conv (+SiLU): writes xc (dir0) and xc2 (dir1)
    conv_fused<<<(CDIM / 8) * BB * NCHK / 256, 256, 0, stream>>>(
        zx, conv_w, conv_b, conv_wb, conv_bb, xc, xc2);

    // 2. per-direction branch; dir1's final accumulates into xc (orig coords)
    for (int dir = 0; dir < 2; dir++) {
        const float* dtb = dir ? dt_biasb : dt_bias;
        const float* Al  = dir ? A_b_log  : A_log;
        const float* Dd  = dir ? D_b      : Dp;
        unsigned short* xb = dir ? xc2 : xc;

        ssd_state<<<BH * NC, 256, 0, stream>>>(xb, zx, dtb, Al, hbuf, dtsum, dir);
        ssd_interchunk<<<BH * 32, 256, 0, stream>>>(hbuf, dtsum, Al);
        ssd_intra<<<BH * NC, 256, 0, stream>>>(xb, hbuf, zx, dtb, Al, Dd, dir);
        branch_final<<<MROWS, 256, 0, stream>>>(xb, zx, norm_w, xc, dir);
    }

    // 3. out = (y_fw + rev(y_bw)) @ out_proj_w^T  (single MFMA GEMM)
    {
        dim3 grid(DM / 128, MROWS / 128);
        gemm_mfma<1><<<grid, 256, 0, stream>>>(xc, CDIM, wbout, DI, out, DM, DM);
    }
}

// Round 8
// 487.112 us; speedup vs baseline: 13.1014x; 1.0537x over previous
//
#include <hip/hip_runtime.h>
#include <hip/hip_bf16.h>
#include <math.h>

#define BB 2
#define LL 4096
#define DM 1024
#define DIP 4240
#define DIPP 4352          // padded N for in-proj (34*128)
#define DI 2048
#define NH 16
#define HD 128
#define DS 64
#define CDIM 2176
#define MROWS (BB*LL)
#define Q 64
#define NC (LL/Q)
#define BH (BB*NH)
#define STR 72             // LDS row stride (ushorts): 144B = 36 dwords -> 2-way banks
#define CCH 16             // conv rows per thread
#define NCHK (LL/CCH)      // conv chunks per batch

typedef __attribute__((ext_vector_type(8))) short bf16x8;
typedef __attribute__((ext_vector_type(4))) float f32x4;

__device__ __forceinline__ float silu_f(float x) { return x / (1.f + expf(-x)); }
__device__ __forceinline__ float softplus_f(float x) {
    return fmaxf(x, 0.f) + log1pf(expf(-fabsf(x)));
}
__device__ __forceinline__ float bf2f(unsigned short u) {
    return __uint_as_float(((unsigned int)u) << 16);
}
__device__ __forceinline__ unsigned short f2bf(float f) {
    unsigned int x = __float_as_uint(f);
    return (unsigned short)((x + 0x7fff + ((x >> 16) & 1)) >> 16);
}
__device__ __forceinline__ void gll16(const void* g, void* l) {
    __builtin_amdgcn_global_load_lds(
        (const __attribute__((address_space(1))) void*)g,
        (__attribute__((address_space(3))) void*)l,
        16, 0, 0);
}

// ---------------------------------------------------------------------------
// fp32 -> bf16 weight conversion with optional row padding (pad rows = 0)
// ---------------------------------------------------------------------------
__global__ __launch_bounds__(256)
void cvt_pad(const float* __restrict__ in, unsigned short* __restrict__ out,
             int rows_real, int rows_pad, int cols)
{
    int idx = blockIdx.x * 256 + threadIdx.x;
    int cols4 = cols >> 2;
    int total = rows_pad * cols4;
    if (idx >= total) return;
    int row = idx / cols4;
    int c4 = (idx - row * cols4) * 4;
    ushort4 o;
    if (row < rows_real) {
        float4 v = *reinterpret_cast<const float4*>(&in[(size_t)row * cols + c4]);
        o.x = f2bf(v.x); o.y = f2bf(v.y); o.z = f2bf(v.z); o.w = f2bf(v.w);
    } else {
        o = make_ushort4(0, 0, 0, 0);
    }
    *reinterpret_cast<ushort4*>(&out[(size_t)row * cols + c4]) = o;
}

// ---------------------------------------------------------------------------
// u fp32 -> bf16 (contiguous, 8 elems/thread)
// ---------------------------------------------------------------------------
__global__ __launch_bounds__(256)
void ucvt(const float* __restrict__ u, unsigned short* __restrict__ ub)
{
    int idx = blockIdx.x * 256 + threadIdx.x;    // MROWS*DM/8
    const float* src = u + (size_t)idx * 8;
    float4 a = *reinterpret_cast<const float4*>(src);
    float4 b = *reinterpret_cast<const float4*>(src + 4);
    unsigned short o[8];
    o[0] = f2bf(a.x); o[1] = f2bf(a.y); o[2] = f2bf(a.z); o[3] = f2bf(a.w);
    o[4] = f2bf(b.x); o[5] = f2bf(b.y); o[6] = f2bf(b.z); o[7] = f2bf(b.w);
    *reinterpret_cast<uint4*>(&ub[(size_t)idx * 8]) = *reinterpret_cast<const uint4*>(o);
}

// ---------------------------------------------------------------------------
// MFMA bf16 GEMM, m97 structure: 128x128 tile, 4 waves (2x2), BK=32.
//   C[M][N](ldc) = A_bf16[M][K](lda) * B_bf16[N][K]^T
// OMODE: 0 = write bf16 bounded by Nreal, 1 = write f32
// XCD-aware block swizzle (T1): grid size must be a multiple of 8.
// ---------------------------------------------------------------------------
template<int OMODE>
__global__ __launch_bounds__(256)
void gemm_mfma(const unsigned short* __restrict__ Ap, int lda,
               const unsigned short* __restrict__ Bp, int K,
               void* __restrict__ Cp, int ldc, int Nreal)
{
    __shared__ alignas(16) unsigned short As[128 * 32];
    __shared__ alignas(16) unsigned short Bs[128 * 32];

    const int t = threadIdx.x;
    const int l = t & 63;

    // XCD swizzle: blocks with lin%8==k (same XCD) get a contiguous tile range
    int lin = blockIdx.y * gridDim.x + blockIdx.x;
    int nwg = gridDim.x * gridDim.y;
    int swz = (lin & 7) * (nwg >> 3) + (lin >> 3);
    int bxs = swz % gridDim.x, bys = swz / gridDim.x;

    const int bm = bys * 128, bn = bxs * 128;
    const int wm = ((t >> 6) >> 1) * 64, wn = ((t >> 6) & 1) * 64;

    f32x4 acc[4][4];
    #pragma unroll
    for (int i = 0; i < 4; i++)
        #pragma unroll
        for (int j = 0; j < 4; j++)
            acc[i][j] = (f32x4){0.f, 0.f, 0.f, 0.f};

    for (int k0 = 0; k0 < K; k0 += 32) {
        #pragma unroll
        for (int i = 0; i < 2; i++) {
            int c = i * 256 + t;
            int row = c >> 2, ke = (c & 3) * 8;
            gll16(Ap + (size_t)(bm + row) * lda + k0 + ke, (char*)&As[0] + c * 16);
        }
        #pragma unroll
        for (int i = 0; i < 2; i++) {
            int c = i * 256 + t;
            int row = c >> 2, ke = (c & 3) * 8;
            gll16(Bp + (size_t)(bn + row) * K + k0 + ke, (char*)&Bs[0] + c * 16);
        }
        __syncthreads();

        bf16x8 af[4], bfr[4];
        #pragma unroll
        for (int mi = 0; mi < 4; mi++)
            af[mi] = *reinterpret_cast<const bf16x8*>(
                &As[(wm + mi * 16 + (l & 15)) * 32 + (l >> 4) * 8]);
        #pragma unroll
        for (int nj = 0; nj < 4; nj++)
            bfr[nj] = *reinterpret_cast<const bf16x8*>(
                &Bs[(wn + nj * 16 + (l & 15)) * 32 + (l >> 4) * 8]);
        #pragma unroll
        for (int mi = 0; mi < 4; mi++)
            #pragma unroll
            for (int nj = 0; nj < 4; nj++)
                acc[mi][nj] = __builtin_amdgcn_mfma_f32_16x16x32_bf16(
                    af[mi], bfr[nj], acc[mi][nj], 0, 0, 0);
        __syncthreads();
    }

    const int col_l = l & 15, rgrp = (l >> 4) * 4;
    #pragma unroll
    for (int mi = 0; mi < 4; mi++) {
        #pragma unroll
        for (int r = 0; r < 4; r++) {
            int gm = bm + wm + mi * 16 + rgrp + r;
            #pragma unroll
            for (int nj = 0; nj < 4; nj++) {
                int gn = bn + wn + nj * 16 + col_l;
                float v = acc[mi][nj][r];
                if (OMODE == 0) {
                    if (gn < Nreal)
                        ((unsigned short*)Cp)[(size_t)gm * ldc + gn] = f2bf(v);
                } else {
                    ((float*)Cp)[(size_t)gm * ldc + gn] = v;
                }
            }
        }
    }
}

// ---------------------------------------------------------------------------
// Fused bidirectional depthwise causal conv (k=4) + SiLU, sliding window.
// ---------------------------------------------------------------------------
__global__ __launch_bounds__(256)
void conv_fused(const unsigned short* __restrict__ zx,
                const float* __restrict__ cw0, const float* __restrict__ cb0,
                const float* __restrict__ cw1, const float* __restrict__ cb1,
                unsigned short* __restrict__ x0, unsigned short* __restrict__ x1)
{
    int idx = blockIdx.x * 256 + threadIdx.x;      // 272 * BB * NCHK total
    int c8 = idx % (CDIM / 8);
    int cg = idx / (CDIM / 8);
    int b  = cg >> 8;             // NCHK = 256
    int ci = cg & (NCHK - 1);
    int c  = c8 * 8;
    int s0 = ci * CCH;

    float wt0[4][8], wt1[4][8], bv0[8], bv1[8];
    #pragma unroll
    for (int ch = 0; ch < 8; ch++) {
        float4 q0 = *reinterpret_cast<const float4*>(&cw0[(c + ch) * 4]);
        float4 q1 = *reinterpret_cast<const float4*>(&cw1[(c + ch) * 4]);
        wt0[0][ch] = q0.x; wt0[1][ch] = q0.y; wt0[2][ch] = q0.z; wt0[3][ch] = q0.w;
        wt1[0][ch] = q1.x; wt1[1][ch] = q1.y; wt1[2][ch] = q1.z; wt1[3][ch] = q1.w;
    }
    {
        float4 a0 = *reinterpret_cast<const float4*>(&cb0[c]);
        float4 a1 = *reinterpret_cast<const float4*>(&cb0[c + 4]);
        bv0[0]=a0.x; bv0[1]=a0.y; bv0[2]=a0.z; bv0[3]=a0.w;
        bv0[4]=a1.x; bv0[5]=a1.y; bv0[6]=a1.z; bv0[7]=a1.w;
        float4 d0 = *reinterpret_cast<const float4*>(&cb1[c]);
        float4 d1 = *reinterpret_cast<const float4*>(&cb1[c + 4]);
        bv1[0]=d0.x; bv1[1]=d0.y; bv1[2]=d0.z; bv1[3]=d0.w;
        bv1[4]=d1.x; bv1[5]=d1.y; bv1[6]=d1.z; bv1[7]=d1.w;
    }

    float win[4][8];

    #define LDROW(SL, S) do {                                                  \
        if ((S) >= 0) {                                                        \
            const unsigned short* _src = &zx[((size_t)b * LL + (S)) * DIP + DI + c]; \
            ushort4 _v0 = *reinterpret_cast<const ushort4*>(_src);             \
            ushort4 _v1 = *reinterpret_cast<const ushort4*>(_src + 4);         \
            win[SL][0] = bf2f(_v0.x); win[SL][1] = bf2f(_v0.y);                \
            win[SL][2] = bf2f(_v0.z); win[SL][3] = bf2f(_v0.w);                \
            win[SL][4] = bf2f(_v1.x); win[SL][5] = bf2f(_v1.y);                \
            win[SL][6] = bf2f(_v1.z); win[SL][7] = bf2f(_v1.w);                \
        } else {                                                               \
            _Pragma("unroll")                                                  \
            for (int _e = 0; _e < 8; _e++) win[SL][_e] = 0.f;                  \
        }                                                                      \
    } while (0)

    #define ZROW(SL) do {                                                      \
        _Pragma("unroll")                                                      \
        for (int _e = 0; _e < 8; _e++) win[SL][_e] = 0.f;                      \
    } while (0)

    #define EMIT0(PH, S) do {                                                  \
        float _a[8]; unsigned short _o[8];                                     \
        _Pragma("unroll")                                                      \
        for (int _ch = 0; _ch < 8; _ch++) {                                    \
            _a[_ch] = bv0[_ch];                                                \
            _a[_ch] = fmaf(wt0[0][_ch], win[((PH)+1)&3][_ch], _a[_ch]);        \
            _a[_ch] = fmaf(wt0[1][_ch], win[((PH)+2)&3][_ch], _a[_ch]);        \
            _a[_ch] = fmaf(wt0[2][_ch], win[((PH)+3)&3][_ch], _a[_ch]);        \
            _a[_ch] = fmaf(wt0[3][_ch], win[(PH)&3][_ch], _a[_ch]);            \
            _o[_ch] = f2bf(silu_f(_a[_ch]));                                   \
        }                                                                      \
        *reinterpret_cast<uint4*>(&x0[((size_t)b * LL + (S)) * CDIM + c]) =    \
            *reinterpret_cast<const uint4*>(_o);                               \
    } while (0)

    #define EMIT1(PH, S) do {                                                  \
        float _a[8]; unsigned short _o[8];                                     \
        _Pragma("unroll")                                                      \
        for (int _ch = 0; _ch < 8; _ch++) {                                    \
            _a[_ch] = bv1[_ch];                                                \
            _a[_ch] = fmaf(wt1[0][_ch], win[(PH)&3][_ch], _a[_ch]);            \
            _a[_ch] = fmaf(wt1[1][_ch], win[((PH)+3)&3][_ch], _a[_ch]);        \
            _a[_ch] = fmaf(wt1[2][_ch], win[((PH)+2)&3][_ch], _a[_ch]);        \
            _a[_ch] = fmaf(wt1[3][_ch], win[((PH)+1)&3][_ch], _a[_ch]);        \
            _o[_ch] = f2bf(silu_f(_a[_ch]));                                   \
        }                                                                      \
        *reinterpret_cast<uint4*>(&x1[((size_t)b * LL + (LL + 2 - (S))) * CDIM + c]) = \
            *reinterpret_cast<const uint4*>(_o);                               \
    } while (0)

    LDROW(1, s0 - 3);
    LDROW(2, s0 - 2);
    LDROW(3, s0 - 1);

    for (int it = 0; it < CCH; it += 4) {
        int sb = s0 + it;
        #pragma unroll
        for (int ph = 0; ph < 4; ph++) {
            int s = sb + ph;
            switch (ph) {
            case 0: LDROW(0, s); EMIT0(0, s); if (s >= 3) EMIT1(0, s); break;
            case 1: LDROW(1, s); EMIT0(1, s); if (s >= 3) EMIT1(1, s); break;
            case 2: LDROW(2, s); EMIT0(2, s); if (s >= 3) EMIT1(2, s); break;
            default: LDROW(3, s); EMIT0(3, s); if (s >= 3) EMIT1(3, s); break;
            }
        }
    }
    if (ci == NCHK - 1) {
        ZROW(0); EMIT1(0, LL);
        ZROW(1); EMIT1(1, LL + 1);
        ZROW(2); EMIT1(2, LL + 2);
    }
    #undef LDROW
    #undef ZROW
    #undef EMIT0
    #undef EMIT1
}

// ---------------------------------------------------------------------------
// Chunk states via MFMA: S[p][n] = sum_j X[j][p] * w_j * B_j[n]
// XT transposed+XOR-swizzled; wBT transposed. Wave-parallel dt prefix scan.
// Epilogue bounced through LDS for 128B-coalesced hbuf writes.
// ---------------------------------------------------------------------------
__global__ __launch_bounds__(256)
void ssd_state(const unsigned short* __restrict__ xc, const unsigned short* __restrict__ zx,
               const float* __restrict__ dtb, const float* __restrict__ A_log,
               unsigned short* __restrict__ hbuf, float* __restrict__ dtsum, int dir)
{
    int bh = blockIdx.x / NC;
    int c  = blockIdx.x % NC;
    int b = bh >> 4, h = bh & 15;
    float Ah = -expf(A_log[h]);
    float dtbh = dtb[h];
    int row0 = b * LL + c * Q;

    __shared__ alignas(16) unsigned short XT[128 * STR];
    __shared__ alignas(16) unsigned short wBT[64 * STR];
    __shared__ float dts_s[Q];
    __shared__ float cum_s[Q];

    const int tid = threadIdx.x;
    const int l = tid & 63;
    const int wid = tid >> 6;

    // stage X transposed: XT[p][ j ^ mask(p) ], mask(p)=((p>>3)&7)<<3
    #pragma unroll
    for (int it = 0; it < 4; it++) {
        int idx = it * 256 + tid;
        int j = idx >> 4;
        int pblk = idx & 15;
        const unsigned short* src = &xc[(size_t)(row0 + j) * CDIM + h * HD + pblk * 8];
        ushort4 v0 = *reinterpret_cast<const ushort4*>(src);
        ushort4 v1 = *reinterpret_cast<const ushort4*>(src + 4);
        unsigned short xv[8] = {v0.x, v0.y, v0.z, v0.w, v1.x, v1.y, v1.z, v1.w};
        int jx = j ^ ((pblk & 7) << 3);
        #pragma unroll
        for (int e = 0; e < 8; e++)
            XT[(pblk * 8 + e) * STR + jx] = xv[e];
    }
    // dt + wave-parallel inclusive prefix scan (wave 0 only)
    if (tid < Q) {
        int rr = c * Q + tid;
        int ls = dir ? (LL - 1 - rr) : rr;
        float dtv = softplus_f(bf2f(zx[(size_t)(b * LL + ls) * DIP + (DIP - NH) + h]) + dtbh);
        float ps = dtv;
        #pragma unroll
        for (int o = 1; o < 64; o <<= 1) {
            float t2 = __shfl_up(ps, o);
            if (tid >= o) ps += t2;
        }
        dts_s[tid] = dtv;
        cum_s[tid] = ps;
    }
    __syncthreads();
    float cumlast = cum_s[Q - 1];
    if (tid == 0) dtsum[bh * NC + c] = cumlast;

    // wBT[n][j] = exp(Ah*(cumlast-cum_j))*dt_j * B_j[n]
    #pragma unroll
    for (int it = 0; it < 2; it++) {
        int idx = it * 256 + tid;
        int j = idx >> 3, n0 = (idx & 7) * 8;
        const unsigned short* src = &xc[(size_t)(row0 + j) * CDIM + DI + n0];
        ushort4 v0 = *reinterpret_cast<const ushort4*>(src);
        ushort4 v1 = *reinterpret_cast<const ushort4*>(src + 4);
        unsigned short bv[8] = {v0.x, v0.y, v0.z, v0.w, v1.x, v1.y, v1.z, v1.w};
        float wj = expf(Ah * (cumlast - cum_s[j])) * dts_s[j];
        #pragma unroll
        for (int e = 0; e < 8; e++)
            wBT[(n0 + e) * STR + j] = f2bf(wj * bf2f(bv[e]));
    }
    __syncthreads();

    // S[p][n] = sum_j XT[p][j] wBT[n][j]; wave wid owns rows wid*32..+32
    f32x4 acc[2][4];
    #pragma unroll
    for (int i = 0; i < 2; i++)
        #pragma unroll
        for (int j = 0; j < 4; j++)
            acc[i][j] = (f32x4){0.f, 0.f, 0.f, 0.f};

    const int p0w = wid * 32;
    #pragma unroll
    for (int kk = 0; kk < 2; kk++) {
        bf16x8 af[2], bfr[4];
        #pragma unroll
        for (int mi = 0; mi < 2; mi++) {
            int p = p0w + mi * 16 + (l & 15);
            int col = (kk * 32 + (l >> 4) * 8) ^ (((p >> 3) & 7) << 3);
            af[mi] = *reinterpret_cast<const bf16x8*>(&XT[p * STR + col]);
        }
        #pragma unroll
        for (int nj = 0; nj < 4; nj++)
            bfr[nj] = *reinterpret_cast<const bf16x8*>(
                &wBT[(nj * 16 + (l & 15)) * STR + kk * 32 + (l >> 4) * 8]);
        #pragma unroll
        for (int mi = 0; mi < 2; mi++)
            #pragma unroll
            for (int nj = 0; nj < 4; nj++)
                acc[mi][nj] = __builtin_amdgcn_mfma_f32_16x16x32_bf16(
                    af[mi], bfr[nj], acc[mi][nj], 0, 0, 0);
    }

    // epilogue: S -> LDS (alias XT) -> coalesced 128B hbuf writes
    __syncthreads();
    unsigned short* Sl = &XT[0];   // [128][STR], uses n<64
    #pragma unroll
    for (int mi = 0; mi < 2; mi++)
        #pragma unroll
        for (int r = 0; r < 4; r++) {
            int p = p0w + mi * 16 + (l >> 4) * 4 + r;
            #pragma unroll
            for (int nj = 0; nj < 4; nj++) {
                int n = nj * 16 + (l & 15);
                Sl[p * STR + n] = f2bf(acc[mi][nj][r]);
            }
        }
    __syncthreads();
    size_t hb = ((size_t)c * BH + bh) * (HD * DS);
    #pragma unroll
    for (int it = 0; it < 4; it++) {
        int idx = it * 256 + tid;
        int p = idx >> 3, n0 = (idx & 7) * 8;
        *reinterpret_cast<uint4*>(&hbuf[hb + (size_t)p * DS + n0]) =
            *reinterpret_cast<const uint4*>(&Sl[p * STR + n0]);
    }
}

// ---------------------------------------------------------------------------
// Inter-chunk recurrence (in place: slot c gets h_init BEFORE chunk c).
// ---------------------------------------------------------------------------
__global__ __launch_bounds__(256)
void ssd_interchunk(unsigned short* __restrict__ hbuf, const float* __restrict__ dtsum,
                    const float* __restrict__ A_log)
{
    int bh  = blockIdx.x >> 5;
    int seg = blockIdx.x & 31;
    int h = bh & 15;
    float Ah = -expf(A_log[h]);
    int off = seg * 256 + threadIdx.x;
    float hst = 0.f;
    for (int c = 0; c < NC; c++) {
        size_t idx = ((size_t)c * BH + bh) * (HD * DS) + off;
        float s = bf2f(hbuf[idx]);
        hbuf[idx] = f2bf(hst);
        hst = fmaf(hst, expf(Ah * dtsum[bh * NC + c]), s);
    }
}

// ---------------------------------------------------------------------------
// Intra-chunk output via MFMA. Y = M·X + Pi*(C·h_init) with D folded into
// the diagonal of M. Output bounced through LDS for coalesced writes.
// ---------------------------------------------------------------------------
__global__ __launch_bounds__(256)
void ssd_intra(unsigned short* __restrict__ xc, const unsigned short* __restrict__ hbuf,
               const unsigned short* __restrict__ zx, const float* __restrict__ dtb,
               const float* __restrict__ A_log, const float* __restrict__ Dv, int dir)
{
    int bh = blockIdx.x / NC;
    int c  = blockIdx.x % NC;
    int b = bh >> 4, h = bh & 15;
    float Ah = -expf(A_log[h]);
    float Dh = Dv[h];
    float dtbh = dtb[h];
    int row0 = b * LL + c * Q;

    __shared__ alignas(16) unsigned short Cm[64 * STR];
    __shared__ alignas(16) unsigned short Bm[64 * STR];
    __shared__ alignas(16) unsigned short Mw[64 * STR];
    __shared__ alignas(16) unsigned short XT[128 * STR];
    __shared__ alignas(16) unsigned short hm[128 * STR];
    __shared__ float dts_s[Q];
    __shared__ float cum_s[Q];

    const int tid = threadIdx.x;
    const int l = tid & 63;
    const int wid = tid >> 6;

    // ---- stage XT (transposed + swizzled) ----
    #pragma unroll
    for (int it = 0; it < 4; it++) {
        int idx = it * 256 + tid;
        int j = idx >> 4;
        int pblk = idx & 15;
        const unsigned short* src = &xc[(size_t)(row0 + j) * CDIM + h * HD + pblk * 8];
        ushort4 v0 = *reinterpret_cast<const ushort4*>(src);
        ushort4 v1 = *reinterpret_cast<const ushort4*>(src + 4);
        unsigned short xv[8] = {v0.x, v0.y, v0.z, v0.w, v1.x, v1.y, v1.z, v1.w};
        int jx = j ^ ((pblk & 7) << 3);
        #pragma unroll
        for (int e = 0; e < 8; e++)
            XT[(pblk * 8 + e) * STR + jx] = xv[e];
    }
    // ---- stage B, C (row-major, K=n) ----
    #pragma unroll
    for (int it = 0; it < 2; it++) {
        int idx = it * 256 + tid;
        int j = idx >> 3, n0 = (idx & 7) * 8;
        *reinterpret_cast<uint4*>(&Bm[j * STR + n0]) =
            *reinterpret_cast<const uint4*>(&xc[(size_t)(row0 + j) * CDIM + DI + n0]);
        *reinterpret_cast<uint4*>(&Cm[j * STR + n0]) =
            *reinterpret_cast<const uint4*>(&xc[(size_t)(row0 + j) * CDIM + DI + DS + n0]);
    }
    // ---- stage h_init [p][n] ----
    {
        size_t hb = ((size_t)c * BH + bh) * (HD * DS);
        #pragma unroll
        for (int it = 0; it < 4; it++) {
            int idx = it * 256 + tid;
            int p = idx >> 3, n0 = (idx & 7) * 8;
            *reinterpret_cast<uint4*>(&hm[p * STR + n0]) =
                *reinterpret_cast<const uint4*>(&hbuf[hb + (size_t)p * DS + n0]);
        }
    }
    // dt + wave-parallel inclusive prefix scan (wave 0 only)
    if (tid < Q) {
        int rr = c * Q + tid;
        int ls = dir ? (LL - 1 - rr) : rr;
        float dtv = softplus_f(bf2f(zx[(size_t)(b * LL + ls) * DIP + (DIP - NH) + h]) + dtbh);
        float ps = dtv;
        #pragma unroll
        for (int o = 1; o < 64; o <<= 1) {
            float t2 = __shfl_up(ps, o);
            if (tid >= o) ps += t2;
        }
        dts_s[tid] = dtv;
        cum_s[tid] = ps;
    }
    __syncthreads();

    // ---- phase 1: G = C·B^T -> masked/weighted + D on diagonal -> Mw ----
    {
        const int i0 = (wid >> 1) * 32, j0 = (wid & 1) * 32;
        f32x4 g[2][2];
        #pragma unroll
        for (int i = 0; i < 2; i++)
            #pragma unroll
            for (int j = 0; j < 2; j++)
                g[i][j] = (f32x4){0.f, 0.f, 0.f, 0.f};
        #pragma unroll
        for (int kk = 0; kk < 2; kk++) {
            bf16x8 ca[2], bb[2];
            #pragma unroll
            for (int mi = 0; mi < 2; mi++)
                ca[mi] = *reinterpret_cast<const bf16x8*>(
                    &Cm[(i0 + mi * 16 + (l & 15)) * STR + kk * 32 + (l >> 4) * 8]);
            #pragma unroll
            for (int nj = 0; nj < 2; nj++)
                bb[nj] = *reinterpret_cast<const bf16x8*>(
                    &Bm[(j0 + nj * 16 + (l & 15)) * STR + kk * 32 + (l >> 4) * 8]);
            #pragma unroll
            for (int mi = 0; mi < 2; mi++)
                #pragma unroll
                for (int nj = 0; nj < 2; nj++)
                    g[mi][nj] = __builtin_amdgcn_mfma_f32_16x16x32_bf16(
                        ca[mi], bb[nj], g[mi][nj], 0, 0, 0);
        }
        #pragma unroll
        for (int mi = 0; mi < 2; mi++)
            #pragma unroll
            for (int nj = 0; nj < 2; nj++)
                #pragma unroll
                for (int r = 0; r < 4; r++) {
                    int i = i0 + mi * 16 + (l >> 4) * 4 + r;
                    int j = j0 + nj * 16 + (l & 15);
                    float wgt = 0.f;
                    if (j < i)       wgt = expf(Ah * (cum_s[i] - cum_s[j])) * dts_s[j];
                    else if (j == i) wgt = dts_s[j];
                    float mv = g[mi][nj][r] * wgt + (j == i ? Dh : 0.f);
                    Mw[i * STR + j] = f2bf(mv);
                }
    }
    __syncthreads();

    // ---- phase 2: Y = Mw·X (via XT) + Pi * Cm·hm ----
    const int yi0 = (wid >> 1) * 32, yp0 = (wid & 1) * 64;
    f32x4 y1[2][4], y2[2][4];
    #pragma unroll
    for (int i = 0; i < 2; i++)
        #pragma unroll
        for (int j = 0; j < 4; j++) {
            y1[i][j] = (f32x4){0.f, 0.f, 0.f, 0.f};
            y2[i][j] = (f32x4){0.f, 0.f, 0.f, 0.f};
        }
    #pragma unroll
    for (int kk = 0; kk < 2; kk++) {
        bf16x8 ma[2], xb[4];
        #pragma unroll
        for (int mi = 0; mi < 2; mi++)
            ma[mi] = *reinterpret_cast<const bf16x8*>(
                &Mw[(yi0 + mi * 16 + (l & 15)) * STR + kk * 32 + (l >> 4) * 8]);
        #pragma unroll
        for (int nj = 0; nj < 4; nj++) {
            int p = yp0 + nj * 16 + (l & 15);
            int col = (kk * 32 + (l >> 4) * 8) ^ (((p >> 3) & 7) << 3);
            xb[nj] = *reinterpret_cast<const bf16x8*>(&XT[p * STR + col]);
        }
        #pragma unroll
        for (int mi = 0; mi < 2; mi++)
            #pragma unroll
            for (int nj = 0; nj < 4; nj++)
                y1[mi][nj] = __builtin_amdgcn_mfma_f32_16x16x32_bf16(
                    ma[mi], xb[nj], y1[mi][nj], 0, 0, 0);
    }
    #pragma unroll
    for (int kk = 0; kk < 2; kk++) {
        bf16x8 ca[2], hbf[4];
        #pragma unroll
        for (int mi = 0; mi < 2; mi++)
            ca[mi] = *reinterpret_cast<const bf16x8*>(
                &Cm[(yi0 + mi * 16 + (l & 15)) * STR + kk * 32 + (l >> 4) * 8]);
        #pragma unroll
        for (int nj = 0; nj < 4; nj++)
            hbf[nj] = *reinterpret_cast<const bf16x8*>(
                &hm[(yp0 + nj * 16 + (l & 15)) * STR + kk * 32 + (l >> 4) * 8]);
        #pragma unroll
        for (int mi = 0; mi < 2; mi++)
            #pragma unroll
            for (int nj = 0; nj < 4; nj++)
                y2[mi][nj] = __builtin_amdgcn_mfma_f32_16x16x32_bf16(
                    ca[mi], hbf[nj], y2[mi][nj], 0, 0, 0);
    }
    __syncthreads();   // all XT reads done before aliasing it with Y

    // ---- epilogue: Y -> LDS (alias XT) -> coalesced global write ----
    unsigned short* Yl = &XT[0];   // [64][136]
    #pragma unroll
    for (int mi = 0; mi < 2; mi++)
        #pragma unroll
        for (int r = 0; r < 4; r++) {
            int i = yi0 + mi * 16 + (l >> 4) * 4 + r;
            float Pi = expf(Ah * cum_s[i]);
            #pragma unroll
            for (int nj = 0; nj < 4; nj++) {
                int p = yp0 + nj * 16 + (l & 15);
                Yl[i * 136 + p] = f2bf(y1[mi][nj][r] + Pi * y2[mi][nj][r]);
            }
        }
    __syncthreads();
    #pragma unroll
    for (int it = 0; it < 4; it++) {
        int idx = it * 256 + tid;
        int i = idx >> 4, p0 = (idx & 15) * 8;
        *reinterpret_cast<uint4*>(&xc[(size_t)(row0 + i) * CDIM + h * HD + p0]) =
            *reinterpret_cast<const uint4*>(&Yl[i * 136 + p0]);
    }
}

// ---------------------------------------------------------------------------
// Merged gated RMSNorm for BOTH directions, one pass, one write:
//   out[l] = (v_fw[l]*s_fw + v_bw[l]*s_bw) * nw,  v_bw from xc2 row LL-1-l.
// ---------------------------------------------------------------------------
__global__ __launch_bounds__(256)
void branch_final2(unsigned short* __restrict__ xc_fw, const unsigned short* __restrict__ xc_bw,
                   const unsigned short* __restrict__ zx, const float* __restrict__ nw)
{
    int row = blockIdx.x;              // original coords: b*LL + l
    int ll = row & (LL - 1);
    int b  = row >> 12;

    unsigned short* yfw = xc_fw + (size_t)row * CDIM;
    const unsigned short* ybw = xc_bw + ((size_t)b * LL + (LL - 1 - ll)) * CDIM;
    const unsigned short* zrow = zx + (size_t)row * DIP;
    int c = threadIdx.x * 8;

    float vf[8], vb[8];
    float sf = 0.f, sb = 0.f;
    {
        ushort4 f0 = *reinterpret_cast<const ushort4*>(&yfw[c]);
        ushort4 f1 = *reinterpret_cast<const ushort4*>(&yfw[c + 4]);
        ushort4 w0 = *reinterpret_cast<const ushort4*>(&ybw[c]);
        ushort4 w1 = *reinterpret_cast<const ushort4*>(&ybw[c + 4]);
        ushort4 z0 = *reinterpret_cast<const ushort4*>(&zrow[c]);
        ushort4 z1 = *reinterpret_cast<const ushort4*>(&zrow[c + 4]);
        unsigned short fv[8] = {f0.x, f0.y, f0.z, f0.w, f1.x, f1.y, f1.z, f1.w};
        unsigned short wv[8] = {w0.x, w0.y, w0.z, w0.w, w1.x, w1.y, w1.z, w1.w};
        unsigned short zv[8] = {z0.x, z0.y, z0.z, z0.w, z1.x, z1.y, z1.z, z1.w};
        #pragma unroll
        for (int ch = 0; ch < 8; ch++) {
            float g = silu_f(bf2f(zv[ch]));
            float a = bf2f(fv[ch]) * g;
            float d = bf2f(wv[ch]) * g;
            vf[ch] = a; vb[ch] = d;
            sf = fmaf(a, a, sf);
            sb = fmaf(d, d, sb);
        }
    }
    #pragma unroll
    for (int o = 32; o > 0; o >>= 1) {
        sf += __shfl_down(sf, o);
        sb += __shfl_down(sb, o);
    }
    __shared__ float redf[4], redb[4];
    if ((threadIdx.x & 63) == 0) {
        redf[threadIdx.x >> 6] = sf;
        redb[threadIdx.x >> 6] = sb;
    }
    __syncthreads();
    sf = redf[0] + redf[1] + redf[2] + redf[3];
    sb = redb[0] + redb[1] + redb[2] + redb[3];
    float scf = rsqrtf(sf * (1.f / DI) + 1e-5f);
    float scb = rsqrtf(sb * (1.f / DI) + 1e-5f);

    float w[8];
    {
        float4 w0 = *reinterpret_cast<const float4*>(&nw[c]);
        float4 w1 = *reinterpret_cast<const float4*>(&nw[c + 4]);
        w[0] = w0.x; w[1] = w0.y; w[2] = w0.z; w[3] = w0.w;
        w[4] = w1.x; w[5] = w1.y; w[6] = w1.z; w[7] = w1.w;
    }
    unsigned short o[8];
    #pragma unroll
    for (int ch = 0; ch < 8; ch++)
        o[ch] = f2bf((vf[ch] * scf + vb[ch] * scb) * w[ch]);
    *reinterpret_cast<uint4*>(&yfw[c]) = *reinterpret_cast<const uint4*>(o);
}

// ---------------------------------------------------------------------------
extern "C" void kernel_launch(void* const* d_in, const int* in_sizes, int n_in,
                              void* d_out, int out_size, void* d_ws, size_t ws_size,
                              hipStream_t stream)
{
    const float* u       = (const float*)d_in[0];
    const float* w_in    = (const float*)d_in[1];
    const float* conv_w  = (const float*)d_in[2];
    const float* conv_b  = (const float*)d_in[3];
    const float* conv_wb = (const float*)d_in[4];
    const float* conv_bb = (const float*)d_in[5];
    const float* dt_bias  = (const float*)d_in[6];
    const float* dt_biasb = (const float*)d_in[7];
    const float* A_log   = (const float*)d_in[8];
    const float* A_b_log = (const float*)d_in[9];
    const float* Dp      = (const float*)d_in[10];
    const float* D_b     = (const float*)d_in[11];
    const float* norm_w  = (const float*)d_in[12];
    const float* w_out   = (const float*)d_in[13];
    float* out = (float*)d_out;

    unsigned short* zx    = (unsigned short*)d_ws;               // MROWS*DIP
    unsigned short* xc    = zx + (size_t)MROWS * DIP;            // MROWS*CDIM
    unsigned short* xc2   = xc + (size_t)MROWS * CDIM;           // MROWS*CDIM
    unsigned short* hb_ub = xc2 + (size_t)MROWS * CDIM;          // max(hbuf, ub)
    unsigned short* wbin  = hb_ub + (size_t)NC * BH * HD * DS;   // DIPP*DM
    unsigned short* wbout = wbin + (size_t)DIPP * DM;            // DM*DI
    float* dtsum = (float*)(wbout + (size_t)DM * DI);            // BH*NC

    unsigned short* ub   = hb_ub;   // live: step 0-1 only
    unsigned short* hbuf = hb_ub;   // live: step 2 onward

    // 0. weight + activation conversion to bf16
    cvt_pad<<<(DIPP * (DM / 4) + 255) / 256, 256, 0, stream>>>(w_in, wbin, DIP, DIPP, DM);
    cvt_pad<<<(DM * (DI / 4) + 255) / 256, 256, 0, stream>>>(w_out, wbout, DM, DM, DI);
    ucvt<<<(MROWS * DM / 8) / 256, 256, 0, stream>>>(u, ub);

    // 1. zxbcdt = u @ in_proj_w^T  (bf16 out, MFMA)
    {
        dim3 grid(DIPP / 128, MROWS / 128);
        gemm_mfma<0><<<grid, 256, 0, stream>>>(ub, DM, wbin, DM, zx, DIP, DIP);
    }

    // 1b. fused bidirectional conv (+SiLU): writes xc (dir0) and xc2 (dir1)
    conv_fused<<<(CDIM / 8) * BB * NCHK / 256, 256, 0, stream>>>(
        zx, conv_w, conv_b, conv_wb, conv_bb, xc, xc2);

    // 2. per-direction SSD; then one merged gated-RMSNorm pass
    for (int dir = 0; dir < 2; dir++) {
        const float* dtb = dir ? dt_biasb : dt_bias;
        const float* Al  = dir ? A_b_log  : A_log;
        const float* Dd  = dir ? D_b      : Dp;
        unsigned short* xb = dir ? xc2 : xc;

        ssd_state<<<BH * NC, 256, 0, stream>>>(xb, zx, dtb, Al, hbuf, dtsum, dir);
        ssd_interchunk<<<BH * 32, 256, 0, stream>>>(hbuf, dtsum, Al);
        ssd_intra<<<BH * NC, 256, 0, stream>>>(xb, hbuf, zx, dtb, Al, Dd, dir);
    }
    branch_final2<<<MROWS, 256, 0, stream>>>(xc, xc2, zx, norm_w);

    // 3. out = (y_fw + rev(y_bw)) @ out_proj_w^T  (single MFMA GEMM)
    {
        dim3 grid(DM / 128, MROWS / 128);
        gemm_mfma<1><<<grid, 256, 0, stream>>>(xc, CDIM, wbout, DI, out, DM, DM);
    }
}